// Round 1
// baseline (1634.262 us; speedup 1.0000x reference)
//
#include <hip/hip_runtime.h>
#include <cstddef>

// FAN_39273180955145 — round 11. r10 counters: MfmaUtil 9.4, VALUBusy 33,
// Occupancy 24 (1 block/CU, 8 waves), HBM 2% -> latency/occupancy-bound, not
// any pipe. LDS (129.5KB) forbids 2 blocks/CU, so: 1024-thread block = 16
// waves = 4 waves/SIMD (VGPR cap 128 = exactly the r10 allocation).
// Work remap vs r8/r10 (math identical, passed absmax 9.8e-4):
//  * kh/v tiles: 16 units -> 1 per wave (was 2 per wave via j loop).
//  * embed/c_all/final-store: spread over 16 waves.
//  * scores+exp+PV: wave pair (w, w+8) splits the 4 mt subtiles 2/2; private
//    oacc halves merged at layer end by raw f32 register dump through the
//    dead khL+vt space (2 rounds x 4 slots, xor-swizzled chunks), ls partials
//    via a 2KB lsx buffer. LN epilogue on waves 0-7 (they own merged oacc).
// Everything else (analytic 2-value log-kernel, fixed-max softmax, dtype
// detector, swizzled hL/vt/khL layouts, prep + MLP kernels) unchanged.

typedef unsigned short u16;
typedef unsigned int u32;
typedef short short8 __attribute__((ext_vector_type(8)));
typedef u32 u32x2 __attribute__((ext_vector_type(2)));
typedef float floatx16 __attribute__((ext_vector_type(16)));
typedef float f32x4 __attribute__((ext_vector_type(4)));

__device__ __forceinline__ float b2f(u16 u){ return __uint_as_float(((u32)u) << 16); }
__device__ __forceinline__ u16 f2b(float f){
  u32 u = __float_as_uint(f);
  return (u16)((u + 0x7fffu + ((u >> 16) & 1u)) >> 16);
}
// flagged input load: f32 ? fp32 : bf16; non-finite -> 0
__device__ __forceinline__ float ldf(const u16* p, size_t i, int f32){
  float v = f32 ? ((const float*)p)[i] : b2f(p[i]);
  return __builtin_isfinite(v) ? v : 0.f;
}
__device__ __forceinline__ u32 pk2(float a, float b){
  return ((u32)f2b(b) << 16) | (u32)f2b(a);
}
// [rows][128 bf16] LDS region, 256B rows, 16B-chunk xor swizzle (2-way max = free)
__device__ __forceinline__ int swz(int row, int ch){ return (row << 8) | ((ch ^ (row & 15)) << 4); }
__device__ __forceinline__ floatx16 fz(){
  floatx16 z;
#pragma unroll
  for (int i = 0; i < 16; ++i) z[i] = 0.f;
  return z;
}
__device__ __forceinline__ floatx16 MF(short8 a, short8 b, floatx16 c){
  return __builtin_amdgcn_mfma_f32_32x32x16_bf16(a, b, c, 0, 0, 0);
}
// C-layout 32x32 tile (by value) -> k-chunk A-fragment via xor-32 exchange (r4-verified).
__device__ __forceinline__ short8 frag_from(floatx16 cv, int half, int q5){
  int r0 = half * 8;
  u32 e01 = pk2(cv[r0 + 0], cv[r0 + 1]);
  u32 e23 = pk2(cv[r0 + 2], cv[r0 + 3]);
  u32 o01 = pk2(cv[r0 + 4], cv[r0 + 5]);
  u32 o23 = pk2(cv[r0 + 6], cv[r0 + 7]);
  u32 s0 = q5 ? e01 : o01;
  u32 s1 = q5 ? e23 : o23;
  u32 r0v = __shfl_xor(s0, 32);
  u32 r1v = __shfl_xor(s1, 32);
  union { u32 u[4]; short8 v; } un;
  un.u[0] = q5 ? r0v : e01;
  un.u[1] = q5 ? r1v : e23;
  un.u[2] = q5 ? o01 : r0v;
  un.u[3] = q5 ? o23 : r1v;
  return un.v;
}
// merge scratch: slot s (0..3) = 16KB region inside dead khL (s<2) / vt (s>=2)
__device__ __forceinline__ float* mslot(u16* khL, u16* vt, int s){
  return (s < 2) ? ((float*)khL + (s << 12)) : ((float*)vt + ((s - 2) << 12));
}

// ---------------- dtype detector (r4-verified) ----------------
__global__ __launch_bounds__(256) void k_detect(const u16* x, int* dflag){
  __shared__ int red[256];
  int t = threadIdx.x, cnt = 0;
  for (int i = t; i < 4096; i += 256){
    u16 v = x[2 * i];
    int e = (v >> 7) & 0xFF;
    if (e == 0xFF || e >= 0x90 || (e > 0 && e <= 0x20)) ++cnt;
  }
  red[t] = cnt;
  __syncthreads();
  for (int off = 128; off > 0; off >>= 1){
    if (t < off) red[t] += red[t + off];
    __syncthreads();
  }
  if (t == 0) dflag[0] = (red[0] > 1000) ? 1 : 0;
}

// ---------------- prep kernels ----------------

// Mrow[r][c] = M'[r,c] (row-major, kh A-operand); vWT[d][e] = vW[e][d]; uv = u'.
__global__ __launch_bounds__(128) void k_prepw(const u16* qW, const u16* kW, const u16* vW,
                                               const u16* qb, u16* Mrow, u16* vWT, float* uv,
                                               const int* dflag){
  int fl = dflag[0];
  int i = blockIdx.x >> 7, f = blockIdx.x & 127, e = threadIdx.x;
  size_t qo = (size_t)(i * 128 + e) * 128;   // qW row e
  size_t ko = (size_t)(i * 128 + f) * 128;   // kW row f
  float m = 0.f;
  for (int d = 0; d < 128; ++d) m += ldf(qW, qo + d, fl) * ldf(kW, ko + d, fl);
  const float RS = 0.08838834764831845f;  // 1/sqrt(128)
  Mrow[(i * 128 + e) * 128 + f] = f2b(m * RS);                // M'[e,f] at [e][f]
  vWT[(i * 128 + f) * 128 + e] = f2b(ldf(vW, qo + f, fl));    // vWT[d][e] = vW[e][d]
  __shared__ float red[128];
  red[e] = ldf(kW, ko + e, fl) * ldf(qb, (size_t)i * 128 + e, fl);
  __syncthreads();
  for (int off = 64; off > 0; off >>= 1){
    if (e < off) red[e] += red[e + off];
    __syncthreads();
  }
  if (e == 0) uv[i * 128 + f] = red[0] * RS;
}

__global__ __launch_bounds__(256) void k_h1t(const u16* h1W, u16* h1WT, const int* dflag){
  int fl = dflag[0];
  __shared__ u16 tile[64][130];
  int k0 = blockIdx.x * 64, tid = threadIdx.x;
#pragma unroll 4
  for (int it = 0; it < 32; ++it){
    int r = it * 2 + (tid >> 7), c = tid & 127;
    tile[r][c] = f2b(ldf(h1W, (size_t)(k0 + r) * 128 + c, fl));
  }
  __syncthreads();
#pragma unroll 4
  for (int it = 0; it < 32; ++it){
    int idx = it * 256 + tid, n = idx >> 6, kk = idx & 63;
    h1WT[(size_t)n * 32896 + k0 + kk] = tile[kk][n];
  }
}

// -------- fused embed + 2 attention layers; h in LDS; one block = one batch --------
// 1024 threads = 16 waves (4/SIMD). Wave pair (w, w+8) shares score-group w&7.

__global__ __launch_bounds__(1024) void k_fan(
    const u16* x, const u16* sW, const u16* sb, const u16* hW, const u16* hbe,
    const u16* Mrow, const float* uv, const u16* vWT, const u16* vb,
    const u16* lng, const u16* lnb,
    u16* hgq, u16* se, int qoff, const int* dflag){
  __shared__ alignas(16) u16 hL[32768];    // h   [256 s][128 f], swz, 64KB
  __shared__ alignas(16) u16 vt[16384];    // vT  [128 d][128 t], swz, 32KB (merge scratch at layer end)
  __shared__ alignas(16) u16 khL[16384];   // kh  [128 t][128 f], swz, 32KB (merge scratch at layer end)
  __shared__ float c_all[256];             // c_t, whole layer
  __shared__ float u_lds[128];             // u' for current layer
  __shared__ float lsx[8][64];             // ls partials from waves 8..15
  int fl = dflag[0];
  int bl = blockIdx.x;
  int b = qoff + bl;
  int tid = threadIdx.x, w = tid >> 6, lane = tid & 63, l31 = lane & 31, q5 = lane >> 5;
  size_t xo = (size_t)b * 272;
  const float LKOFF = -20.72326584f;       // ln(1e-9); off-diag log-kernel value

  // scalar embedding (lanes 0..127)
  if (tid < 128){
    float acc = ldf(sb, tid, fl);
#pragma unroll
    for (int j = 0; j < 16; ++j) acc += ldf(x, xo + j, fl) * ldf(sW, (size_t)j * 128 + tid, fl);
    se[(size_t)b * 128 + tid] = f2b(acc);
  }
  // history embedding -> hL (4096 16B chunks over 1024 threads)
#pragma unroll
  for (int it = 0; it < 4; ++it){
    int c = it * 1024 + tid, s = c >> 4, ch = c & 15;
    float xv = ldf(x, xo + 16 + s, fl);
    short8 r;
#pragma unroll
    for (int j = 0; j < 8; ++j)
      r[j] = (short)f2b(xv * ldf(hW, ch * 8 + j, fl) + ldf(hbe, ch * 8 + j, fl));
    *(short8*)((char*)hL + swz(s, ch)) = r;
  }

#pragma unroll 1
  for (int li = 0; li < 2; ++li){
    const u16* Mri  = Mrow + li * 16384;
    const u16* vWTi = vWT + li * 16384;
    if (tid < 128) u_lds[tid] = uv[li * 128 + tid];
    __syncthreads();                 // hL (embed/prev epilogue) + u_lds visible

    // ---- c_all[t] = u'.h_t; 16 waves x 16 rows, 4 lanes per row (k-quarters)
    {
      int row = 16 * w + (lane & 15);
      int kq = lane >> 4;            // 0..3
      float dot = 0.f;
#pragma unroll
      for (int kc = 0; kc < 4; ++kc){
        int ch = 4 * kc + kq;
        short8 hv = *(const short8*)((char*)hL + swz(row, ch));
#pragma unroll
        for (int j = 0; j < 8; ++j) dot += u_lds[ch * 8 + j] * b2f(hv[j]);
      }
      dot += __shfl_xor(dot, 16);
      dot += __shfl_xor(dot, 32);
      if (kq == 0) c_all[row] = dot;
    }

    float ls_tot = 0.f;
    floatx16 oacc[4];
#pragma unroll
    for (int nt = 0; nt < 4; ++nt) oacc[nt] = fz();
    int sg = w & 7, mh = w >> 3;
    int scol = 32 * sg + l31;

#pragma unroll 1
    for (int tt = 0; tt < 2; ++tt){
      int t0 = tt * 128;
      __syncthreads();               // prior tile's khL/vt reads done; c_all visible
      // ---- kh-tile: khL[t][f] = sum_e M'[f,e] h[t0+t][e]; 16 units -> 1/wave
      {
        int mtv = w & 3, ntv = w >> 2;
        floatx16 ka = fz();
#pragma unroll 2
        for (int kc = 0; kc < 8; ++kc){
          short8 av = *(const short8*)(Mri + (32 * mtv + l31) * 128 + kc * 16 + q5 * 8);
          short8 bh = *(const short8*)((char*)hL + swz(t0 + 32 * ntv + l31, 2 * kc + q5));
          ka = MF(av, bh, ka);
        }
        int tloc = 32 * ntv + l31;
#pragma unroll
        for (int qd = 0; qd < 4; ++qd){
          // regs 4qd..4qd+3 -> frow = 32mtv + 8qd + 4q5 + (0..3): one 16B chunk
          u32x2 pv;
          pv.x = pk2(ka[4 * qd + 0], ka[4 * qd + 1]);
          pv.y = pk2(ka[4 * qd + 2], ka[4 * qd + 3]);
          *(u32x2*)((char*)khL + swz(tloc, 4 * mtv + qd) + 8 * q5) = pv;
        }
      }
      // ---- v-tile: vt[d][t] = sum_e vWT[d][e] h[t0+t][e] + vb[d]; 16 units -> 1/wave
      {
        int mtv = w & 3, ntv = w >> 2;
        float vbl = ldf(vb, (size_t)li * 128 + 32 * mtv + l31, fl);
        floatx16 va = fz();
#pragma unroll 2
        for (int kc = 0; kc < 8; ++kc){
          short8 av = *(const short8*)(vWTi + (32 * mtv + l31) * 128 + kc * 16 + q5 * 8);
          short8 bh = *(const short8*)((char*)hL + swz(t0 + 32 * ntv + l31, 2 * kc + q5));
          va = MF(av, bh, va);
        }
#pragma unroll
        for (int reg = 0; reg < 16; ++reg){
          int rr = (reg & 3) + 8 * (reg >> 2) + 4 * q5;
          int tloc = 32 * ntv + l31;
          *(u16*)((char*)vt + swz(32 * mtv + rr, tloc >> 3) + (tloc & 7) * 2) =
              f2b(va[reg] + __shfl(vbl, rr));
        }
      }
      __syncthreads();               // khL, vt complete
      // ---- scores + exp + P@V; wave pair splits mt: w<8 -> mt 0,1; w>=8 -> mt 2,3
#pragma unroll 1
      for (int mm = 0; mm < 2; ++mm){
        int mt = 2 * mh + mm;
        floatx16 sa = fz();
#pragma unroll 2
        for (int kc = 0; kc < 8; ++kc){
          short8 ak = *(const short8*)((char*)khL + swz(32 * mt + l31, 2 * kc + q5));
          short8 bq = *(const short8*)((char*)hL + swz(32 * sg + l31, 2 * kc + q5));
          sa = MF(ak, bq, sa);
        }
#pragma unroll
        for (int reg = 0; reg < 16; ++reg){
          int trl = 32 * mt + (reg & 3) + 8 * (reg >> 2) + 4 * q5;
          int tg = t0 + trl;
          float lk = (tg == scol) ? 0.f : LKOFF;
          float v = sa[reg] + c_all[tg] + lk;
          v = fminf(fmaxf(v, -50.f), 50.f);
          float p = __expf(v - 8.f);   // fixed max: softmax shift-invariant
          sa[reg] = p;
          ls_tot += p;
        }
        // pf frags computed BEFORE the bv loads so sa dies here (register diet)
        short8 pf0 = frag_from(sa, 0, q5);
        short8 pf1 = frag_from(sa, 1, q5);
#pragma unroll
        for (int nt = 0; nt < 4; ++nt){
          short8 bv0 = *(const short8*)((char*)vt + swz(32 * nt + l31, 2 * (2 * mt + 0) + q5));
          oacc[nt] = MF(pf0, bv0, oacc[nt]);
          short8 bv1 = *(const short8*)((char*)vt + swz(32 * nt + l31, 2 * (2 * mt + 1) + q5));
          oacc[nt] = MF(pf1, bv1, oacc[nt]);
        }
      }
    }

    // ---- pair merge: oacc(w) += oacc(w+8), ls likewise; khL+vt reused as scratch
    __syncthreads();                   // all khL/vt/hL reads done
    if (w >= 8) lsx[w - 8][lane] = ls_tot;
#pragma unroll 1
    for (int rnd = 0; rnd < 2; ++rnd){
      if (w >= 8 + 4 * rnd && w < 12 + 4 * rnd){
        char* bp = (char*)mslot(khL, vt, w - 8 - 4 * rnd) + lane * 256;
#pragma unroll
        for (int ci = 0; ci < 16; ++ci){
          f32x4 t;
          t[0] = oacc[ci >> 2][4 * (ci & 3) + 0];
          t[1] = oacc[ci >> 2][4 * (ci & 3) + 1];
          t[2] = oacc[ci >> 2][4 * (ci & 3) + 2];
          t[3] = oacc[ci >> 2][4 * (ci & 3) + 3];
          *(f32x4*)(bp + ((ci ^ (lane & 15)) << 4)) = t;
        }
      }
      __syncthreads();
      if (w >= 4 * rnd && w < 4 + 4 * rnd){
        char* bp = (char*)mslot(khL, vt, w - 4 * rnd) + lane * 256;
#pragma unroll
        for (int ci = 0; ci < 16; ++ci){
          f32x4 t = *(const f32x4*)(bp + ((ci ^ (lane & 15)) << 4));
          oacc[ci >> 2][4 * (ci & 3) + 0] += t[0];
          oacc[ci >> 2][4 * (ci & 3) + 1] += t[1];
          oacc[ci >> 2][4 * (ci & 3) + 2] += t[2];
          oacc[ci >> 2][4 * (ci & 3) + 3] += t[3];
        }
      }
      __syncthreads();                 // slot reuse (rnd 0) / merge complete (rnd 1)
    }

    // ---- epilogue (waves 0..7 own merged oacc): /l, +residual, LN, write hL
    if (w < 8){
      ls_tot += lsx[w][lane];
      float l_run = ls_tot + __shfl_xor(ls_tot, 32);
      float linv = 1.f / l_run;
      float gv[4], bbv[4];
#pragma unroll
      for (int nt = 0; nt < 4; ++nt){
        gv[nt]  = ldf(lng, (size_t)li * 128 + 32 * nt + l31, fl);
        bbv[nt] = ldf(lnb, (size_t)li * 128 + 32 * nt + l31, fl);
      }
#pragma unroll
      for (int reg = 0; reg < 16; ++reg){
        int rr = (reg & 3) + 8 * (reg >> 2) + 4 * q5;
        int srow = 32 * sg + rr;
        float lrv = __shfl(linv, rr);
        float s1 = 0.f, s2 = 0.f;
#pragma unroll
        for (int nt = 0; nt < 4; ++nt){
          int d = 32 * nt + l31;
          float res = b2f(*(const u16*)((char*)hL + swz(srow, d >> 3) + (d & 7) * 2));
          float v = oacc[nt][reg] * lrv + res;
          oacc[nt][reg] = v;
          s1 += v; s2 += v * v;
        }
#pragma unroll
        for (int off = 1; off < 32; off <<= 1){ s1 += __shfl_xor(s1, off); s2 += __shfl_xor(s2, off); }
        float mu = s1 * 0.0078125f;
        float rs = rsqrtf(fmaxf(s2 * 0.0078125f - mu * mu, 0.f) + 1e-5f);
#pragma unroll
        for (int nt = 0; nt < 4; ++nt){
          int d = 32 * nt + l31;
          float v = (oacc[nt][reg] - mu) * rs * gv[nt] + bbv[nt];
          *(u16*)((char*)hL + swz(srow, d >> 3) + (d & 7) * 2) = f2b(v);
        }
      }
    }
    __syncthreads();                   // hL update visible before next layer / store
  }

  // final h -> global, coalesced 16B chunks
#pragma unroll
  for (int it = 0; it < 4; ++it){
    int c = it * 1024 + tid, row = c >> 4, ch = c & 15;
    *(short8*)(hgq + (size_t)bl * 32768 + row * 128 + ch * 8) =
        *(const short8*)((char*)hL + swz(row, ch));
  }
}

// ---------------- MLP head ----------------

__global__ __launch_bounds__(256) void k_mlp1(const u16* se, const u16* hgq, const u16* h1WT,
                                              float* part, int qoff, int nb){
  int mb = blockIdx.x, ks = blockIdx.y;
  int tid = threadIdx.x, w = tid >> 6, lane = tid & 63, l31 = lane & 31, q5 = lane >> 5;
  int b0 = mb * 32;
  floatx16 acc = fz();
  const u16* brow = h1WT + (size_t)(32 * w + l31) * 32896;
  int br = b0 + l31;
  const u16* seb = se + (size_t)(qoff + br) * 128;
  const u16* hb = hgq + (size_t)br * 32768;
  for (int kk = 0; kk < 257; ++kk){
    int kbase = ks * 4112 + kk * 16;
    const u16* ap = (kbase < 128) ? (seb + kbase + q5 * 8) : (hb + (kbase - 128) + q5 * 8);
    short8 a = *(const short8*)ap;
    short8 bf = *(const short8*)(brow + kbase + q5 * 8);
    acc = MF(a, bf, acc);
  }
#pragma unroll
  for (int reg = 0; reg < 16; ++reg){
    int rr = (reg & 3) + 8 * (reg >> 2) + 4 * q5;
    part[(size_t)ks * nb * 128 + (size_t)(b0 + rr) * 128 + 32 * w + l31] = acc[reg];
  }
}

__global__ __launch_bounds__(256) void k_mlp1red(const float* part, const u16* h1b, float* z1q,
                                                 const int* dflag, int nb){
  int fl = dflag[0];
  int idx = blockIdx.x * 256 + threadIdx.x;    // 0..nb*128-1
  float s = ldf(h1b, idx & 127, fl);
  size_t stride = (size_t)nb * 128;
#pragma unroll
  for (int ks = 0; ks < 8; ++ks) s += part[(size_t)ks * stride + idx];
  z1q[idx] = fmaxf(s, 0.f);
}

__global__ __launch_bounds__(256) void k_mlp2(const float* z1, const u16* h2W, const u16* h2b,
                                              float* z2, const int* dflag){
  int fl = dflag[0];
  int idx = blockIdx.x * 256 + threadIdx.x;    // 0..131071
  int b = idx >> 6, j = idx & 63;
  float s = ldf(h2b, j, fl);
  const float* zr = z1 + (size_t)b * 128;
  for (int k = 0; k < 128; ++k) s += zr[k] * ldf(h2W, (size_t)k * 64 + j, fl);
  z2[idx] = fmaxf(s, 0.f);
}

__global__ __launch_bounds__(256) void k_mlp3(const float* z2, const u16* h3W, const u16* h3b,
                                              void* out, const int* dflag){
  int fl = dflag[0];
  int b = blockIdx.x * 256 + threadIdx.x;      // 0..2047
  float s = ldf(h3b, 0, fl);
  const float* zr = z2 + (size_t)b * 64;
#pragma unroll
  for (int j = 0; j < 64; ++j) s += zr[j] * ldf(h3W, j, fl);
  if (!__builtin_isfinite(s)) s = 0.f;
  if (fl) ((float*)out)[b] = s;
  else    ((u16*)out)[b] = f2b(s);
}

// ---------------- launch ----------------

extern "C" void kernel_launch(void* const* d_in, const int* in_sizes, int n_in,
                              void* d_out, int out_size, void* d_ws, size_t ws_size,
                              hipStream_t stream) {
  const u16* x   = (const u16*)d_in[0];
  const u16* sW  = (const u16*)d_in[1];
  const u16* sb  = (const u16*)d_in[2];
  const u16* hW  = (const u16*)d_in[3];
  const u16* hb  = (const u16*)d_in[4];
  const u16* qW  = (const u16*)d_in[5];
  const u16* qb  = (const u16*)d_in[6];
  const u16* kW  = (const u16*)d_in[7];
  // d_in[8] = kb : cancels in softmax, unused
  const u16* vW  = (const u16*)d_in[9];
  const u16* vb  = (const u16*)d_in[10];
  const u16* lng = (const u16*)d_in[11];
  const u16* lnb = (const u16*)d_in[12];
  const u16* h1W = (const u16*)d_in[13];
  const u16* h1b = (const u16*)d_in[14];
  const u16* h2W = (const u16*)d_in[15];
  const u16* h2b = (const u16*)d_in[16];
  const u16* h3W = (const u16*)d_in[17];
  const u16* h3b = (const u16*)d_in[18];

  // full-pass mode (r5-r8 ran this branch); quarter mode fallback.
  const int nb = (ws_size >= 153600000ull) ? 2048 : 512;
  const int nq = 2048 / nb;

  char* W = (char*)d_ws;
  size_t o = 0;
  u16*   hg    = (u16*)(W + o); o += (size_t)nb * 65536;   // nb*32768*2
  u16*   h1WT  = (u16*)(W + o); o += 8421376;
  u16*   se    = (u16*)(W + o); o += 524288;               // always full 2048x128 bf16
  u16*   Mrow  = (u16*)(W + o); o += 65536;
  u16*   vWT   = (u16*)(W + o); o += 65536;
  float* uv    = (float*)(W + o); o += 1024;
  float* part  = (float*)(W + o); o += (size_t)nb * 4096;  // 8 * nb*128 * 4B
  float* z1    = (float*)(W + o); o += 1048576;            // always full
  float* z2    = (float*)(W + o); o += 524288;
  int*   dflag = (int*)(W + o);

  k_detect<<<1, 256, 0, stream>>>(x, dflag);
  k_prepw<<<256, 128, 0, stream>>>(qW, kW, vW, qb, Mrow, vWT, uv, dflag);
  k_h1t<<<514, 256, 0, stream>>>(h1W, h1WT, dflag);

  for (int q = 0; q < nq; ++q){
    int qoff = q * nb;
    k_fan<<<nb, 1024, 0, stream>>>(x, sW, sb, hW, hb, Mrow, uv, vWT, vb,
                                   lng, lnb, hg, se, qoff, dflag);
    k_mlp1<<<dim3(nb / 32, 8), 256, 0, stream>>>(se, hg, h1WT, part, qoff, nb);
    k_mlp1red<<<nb / 2, 256, 0, stream>>>(part, h1b, z1 + (size_t)qoff * 128, dflag, nb);
  }

  k_mlp2<<<512, 256, 0, stream>>>(z1, h2W, h2b, z2, dflag);
  k_mlp3<<<8, 256, 0, stream>>>(z2, h3W, h3b, d_out, dflag);
}

// Round 2
// 1631.091 us; speedup vs baseline: 1.0019x; 1.0019x over previous
//
#include <hip/hip_runtime.h>
#include <cstddef>

// FAN_39273180955145 — round 12. r11 post-mortem: the 1024-thread remap
// doubled occupancy (24->47%) as designed, but plain __launch_bounds__(1024)
// let the allocator target 8 waves/EU -> 64 VGPRs -> oacc[4] (64 regs) spilled
// to scratch: hbm_bytes 0.16GB -> 2.42GB/dispatch, 22% HBM, 1380us. Fix:
// __launch_bounds__(1024, 4) = 4 waves/EU min -> 128-VGPR budget (the exact
// spill-free allocation r10 ran with). No other changes vs r11:
//  * kh/v tiles: 16 units -> 1 per wave.
//  * embed/c_all/final-store: spread over 16 waves.
//  * scores+exp+PV: wave pair (w, w+8) splits the 4 mt subtiles 2/2; private
//    oacc halves merged at layer end through dead khL+vt space; lsx buffer.
//  * LN epilogue on waves 0-7.
// Math identical to r8/r10 (passed, absmax 9.8e-4).

typedef unsigned short u16;
typedef unsigned int u32;
typedef short short8 __attribute__((ext_vector_type(8)));
typedef u32 u32x2 __attribute__((ext_vector_type(2)));
typedef float floatx16 __attribute__((ext_vector_type(16)));
typedef float f32x4 __attribute__((ext_vector_type(4)));

__device__ __forceinline__ float b2f(u16 u){ return __uint_as_float(((u32)u) << 16); }
__device__ __forceinline__ u16 f2b(float f){
  u32 u = __float_as_uint(f);
  return (u16)((u + 0x7fffu + ((u >> 16) & 1u)) >> 16);
}
// flagged input load: f32 ? fp32 : bf16; non-finite -> 0
__device__ __forceinline__ float ldf(const u16* p, size_t i, int f32){
  float v = f32 ? ((const float*)p)[i] : b2f(p[i]);
  return __builtin_isfinite(v) ? v : 0.f;
}
__device__ __forceinline__ u32 pk2(float a, float b){
  return ((u32)f2b(b) << 16) | (u32)f2b(a);
}
// [rows][128 bf16] LDS region, 256B rows, 16B-chunk xor swizzle (2-way max = free)
__device__ __forceinline__ int swz(int row, int ch){ return (row << 8) | ((ch ^ (row & 15)) << 4); }
__device__ __forceinline__ floatx16 fz(){
  floatx16 z;
#pragma unroll
  for (int i = 0; i < 16; ++i) z[i] = 0.f;
  return z;
}
__device__ __forceinline__ floatx16 MF(short8 a, short8 b, floatx16 c){
  return __builtin_amdgcn_mfma_f32_32x32x16_bf16(a, b, c, 0, 0, 0);
}
// C-layout 32x32 tile (by value) -> k-chunk A-fragment via xor-32 exchange (r4-verified).
__device__ __forceinline__ short8 frag_from(floatx16 cv, int half, int q5){
  int r0 = half * 8;
  u32 e01 = pk2(cv[r0 + 0], cv[r0 + 1]);
  u32 e23 = pk2(cv[r0 + 2], cv[r0 + 3]);
  u32 o01 = pk2(cv[r0 + 4], cv[r0 + 5]);
  u32 o23 = pk2(cv[r0 + 6], cv[r0 + 7]);
  u32 s0 = q5 ? e01 : o01;
  u32 s1 = q5 ? e23 : o23;
  u32 r0v = __shfl_xor(s0, 32);
  u32 r1v = __shfl_xor(s1, 32);
  union { u32 u[4]; short8 v; } un;
  un.u[0] = q5 ? r0v : e01;
  un.u[1] = q5 ? r1v : e23;
  un.u[2] = q5 ? o01 : r0v;
  un.u[3] = q5 ? o23 : r1v;
  return un.v;
}
// merge scratch: slot s (0..3) = 16KB region inside dead khL (s<2) / vt (s>=2)
__device__ __forceinline__ float* mslot(u16* khL, u16* vt, int s){
  return (s < 2) ? ((float*)khL + (s << 12)) : ((float*)vt + ((s - 2) << 12));
}

// ---------------- dtype detector (r4-verified) ----------------
__global__ __launch_bounds__(256) void k_detect(const u16* x, int* dflag){
  __shared__ int red[256];
  int t = threadIdx.x, cnt = 0;
  for (int i = t; i < 4096; i += 256){
    u16 v = x[2 * i];
    int e = (v >> 7) & 0xFF;
    if (e == 0xFF || e >= 0x90 || (e > 0 && e <= 0x20)) ++cnt;
  }
  red[t] = cnt;
  __syncthreads();
  for (int off = 128; off > 0; off >>= 1){
    if (t < off) red[t] += red[t + off];
    __syncthreads();
  }
  if (t == 0) dflag[0] = (red[0] > 1000) ? 1 : 0;
}

// ---------------- prep kernels ----------------

// Mrow[r][c] = M'[r,c] (row-major, kh A-operand); vWT[d][e] = vW[e][d]; uv = u'.
__global__ __launch_bounds__(128) void k_prepw(const u16* qW, const u16* kW, const u16* vW,
                                               const u16* qb, u16* Mrow, u16* vWT, float* uv,
                                               const int* dflag){
  int fl = dflag[0];
  int i = blockIdx.x >> 7, f = blockIdx.x & 127, e = threadIdx.x;
  size_t qo = (size_t)(i * 128 + e) * 128;   // qW row e
  size_t ko = (size_t)(i * 128 + f) * 128;   // kW row f
  float m = 0.f;
  for (int d = 0; d < 128; ++d) m += ldf(qW, qo + d, fl) * ldf(kW, ko + d, fl);
  const float RS = 0.08838834764831845f;  // 1/sqrt(128)
  Mrow[(i * 128 + e) * 128 + f] = f2b(m * RS);                // M'[e,f] at [e][f]
  vWT[(i * 128 + f) * 128 + e] = f2b(ldf(vW, qo + f, fl));    // vWT[d][e] = vW[e][d]
  __shared__ float red[128];
  red[e] = ldf(kW, ko + e, fl) * ldf(qb, (size_t)i * 128 + e, fl);
  __syncthreads();
  for (int off = 64; off > 0; off >>= 1){
    if (e < off) red[e] += red[e + off];
    __syncthreads();
  }
  if (e == 0) uv[i * 128 + f] = red[0] * RS;
}

__global__ __launch_bounds__(256) void k_h1t(const u16* h1W, u16* h1WT, const int* dflag){
  int fl = dflag[0];
  __shared__ u16 tile[64][130];
  int k0 = blockIdx.x * 64, tid = threadIdx.x;
#pragma unroll 4
  for (int it = 0; it < 32; ++it){
    int r = it * 2 + (tid >> 7), c = tid & 127;
    tile[r][c] = f2b(ldf(h1W, (size_t)(k0 + r) * 128 + c, fl));
  }
  __syncthreads();
#pragma unroll 4
  for (int it = 0; it < 32; ++it){
    int idx = it * 256 + tid, n = idx >> 6, kk = idx & 63;
    h1WT[(size_t)n * 32896 + k0 + kk] = tile[kk][n];
  }
}

// -------- fused embed + 2 attention layers; h in LDS; one block = one batch --------
// 1024 threads = 16 waves (4/SIMD). Wave pair (w, w+8) shares score-group w&7.

__global__ __launch_bounds__(1024, 4) void k_fan(
    const u16* x, const u16* sW, const u16* sb, const u16* hW, const u16* hbe,
    const u16* Mrow, const float* uv, const u16* vWT, const u16* vb,
    const u16* lng, const u16* lnb,
    u16* hgq, u16* se, int qoff, const int* dflag){
  __shared__ alignas(16) u16 hL[32768];    // h   [256 s][128 f], swz, 64KB
  __shared__ alignas(16) u16 vt[16384];    // vT  [128 d][128 t], swz, 32KB (merge scratch at layer end)
  __shared__ alignas(16) u16 khL[16384];   // kh  [128 t][128 f], swz, 32KB (merge scratch at layer end)
  __shared__ float c_all[256];             // c_t, whole layer
  __shared__ float u_lds[128];             // u' for current layer
  __shared__ float lsx[8][64];             // ls partials from waves 8..15
  int fl = dflag[0];
  int bl = blockIdx.x;
  int b = qoff + bl;
  int tid = threadIdx.x, w = tid >> 6, lane = tid & 63, l31 = lane & 31, q5 = lane >> 5;
  size_t xo = (size_t)b * 272;
  const float LKOFF = -20.72326584f;       // ln(1e-9); off-diag log-kernel value

  // scalar embedding (lanes 0..127)
  if (tid < 128){
    float acc = ldf(sb, tid, fl);
#pragma unroll
    for (int j = 0; j < 16; ++j) acc += ldf(x, xo + j, fl) * ldf(sW, (size_t)j * 128 + tid, fl);
    se[(size_t)b * 128 + tid] = f2b(acc);
  }
  // history embedding -> hL (4096 16B chunks over 1024 threads)
#pragma unroll
  for (int it = 0; it < 4; ++it){
    int c = it * 1024 + tid, s = c >> 4, ch = c & 15;
    float xv = ldf(x, xo + 16 + s, fl);
    short8 r;
#pragma unroll
    for (int j = 0; j < 8; ++j)
      r[j] = (short)f2b(xv * ldf(hW, ch * 8 + j, fl) + ldf(hbe, ch * 8 + j, fl));
    *(short8*)((char*)hL + swz(s, ch)) = r;
  }

#pragma unroll 1
  for (int li = 0; li < 2; ++li){
    const u16* Mri  = Mrow + li * 16384;
    const u16* vWTi = vWT + li * 16384;
    if (tid < 128) u_lds[tid] = uv[li * 128 + tid];
    __syncthreads();                 // hL (embed/prev epilogue) + u_lds visible

    // ---- c_all[t] = u'.h_t; 16 waves x 16 rows, 4 lanes per row (k-quarters)
    {
      int row = 16 * w + (lane & 15);
      int kq = lane >> 4;            // 0..3
      float dot = 0.f;
#pragma unroll
      for (int kc = 0; kc < 4; ++kc){
        int ch = 4 * kc + kq;
        short8 hv = *(const short8*)((char*)hL + swz(row, ch));
#pragma unroll
        for (int j = 0; j < 8; ++j) dot += u_lds[ch * 8 + j] * b2f(hv[j]);
      }
      dot += __shfl_xor(dot, 16);
      dot += __shfl_xor(dot, 32);
      if (kq == 0) c_all[row] = dot;
    }

    float ls_tot = 0.f;
    floatx16 oacc[4];
#pragma unroll
    for (int nt = 0; nt < 4; ++nt) oacc[nt] = fz();
    int sg = w & 7, mh = w >> 3;
    int scol = 32 * sg + l31;

#pragma unroll 1
    for (int tt = 0; tt < 2; ++tt){
      int t0 = tt * 128;
      __syncthreads();               // prior tile's khL/vt reads done; c_all visible
      // ---- kh-tile: khL[t][f] = sum_e M'[f,e] h[t0+t][e]; 16 units -> 1/wave
      {
        int mtv = w & 3, ntv = w >> 2;
        floatx16 ka = fz();
#pragma unroll 2
        for (int kc = 0; kc < 8; ++kc){
          short8 av = *(const short8*)(Mri + (32 * mtv + l31) * 128 + kc * 16 + q5 * 8);
          short8 bh = *(const short8*)((char*)hL + swz(t0 + 32 * ntv + l31, 2 * kc + q5));
          ka = MF(av, bh, ka);
        }
        int tloc = 32 * ntv + l31;
#pragma unroll
        for (int qd = 0; qd < 4; ++qd){
          // regs 4qd..4qd+3 -> frow = 32mtv + 8qd + 4q5 + (0..3): one 16B chunk
          u32x2 pv;
          pv.x = pk2(ka[4 * qd + 0], ka[4 * qd + 1]);
          pv.y = pk2(ka[4 * qd + 2], ka[4 * qd + 3]);
          *(u32x2*)((char*)khL + swz(tloc, 4 * mtv + qd) + 8 * q5) = pv;
        }
      }
      // ---- v-tile: vt[d][t] = sum_e vWT[d][e] h[t0+t][e] + vb[d]; 16 units -> 1/wave
      {
        int mtv = w & 3, ntv = w >> 2;
        float vbl = ldf(vb, (size_t)li * 128 + 32 * mtv + l31, fl);
        floatx16 va = fz();
#pragma unroll 2
        for (int kc = 0; kc < 8; ++kc){
          short8 av = *(const short8*)(vWTi + (32 * mtv + l31) * 128 + kc * 16 + q5 * 8);
          short8 bh = *(const short8*)((char*)hL + swz(t0 + 32 * ntv + l31, 2 * kc + q5));
          va = MF(av, bh, va);
        }
#pragma unroll
        for (int reg = 0; reg < 16; ++reg){
          int rr = (reg & 3) + 8 * (reg >> 2) + 4 * q5;
          int tloc = 32 * ntv + l31;
          *(u16*)((char*)vt + swz(32 * mtv + rr, tloc >> 3) + (tloc & 7) * 2) =
              f2b(va[reg] + __shfl(vbl, rr));
        }
      }
      __syncthreads();               // khL, vt complete
      // ---- scores + exp + P@V; wave pair splits mt: w<8 -> mt 0,1; w>=8 -> mt 2,3
#pragma unroll 1
      for (int mm = 0; mm < 2; ++mm){
        int mt = 2 * mh + mm;
        floatx16 sa = fz();
#pragma unroll 2
        for (int kc = 0; kc < 8; ++kc){
          short8 ak = *(const short8*)((char*)khL + swz(32 * mt + l31, 2 * kc + q5));
          short8 bq = *(const short8*)((char*)hL + swz(32 * sg + l31, 2 * kc + q5));
          sa = MF(ak, bq, sa);
        }
#pragma unroll
        for (int reg = 0; reg < 16; ++reg){
          int trl = 32 * mt + (reg & 3) + 8 * (reg >> 2) + 4 * q5;
          int tg = t0 + trl;
          float lk = (tg == scol) ? 0.f : LKOFF;
          float v = sa[reg] + c_all[tg] + lk;
          v = fminf(fmaxf(v, -50.f), 50.f);
          float p = __expf(v - 8.f);   // fixed max: softmax shift-invariant
          sa[reg] = p;
          ls_tot += p;
        }
        // pf frags computed BEFORE the bv loads so sa dies here (register diet)
        short8 pf0 = frag_from(sa, 0, q5);
        short8 pf1 = frag_from(sa, 1, q5);
#pragma unroll
        for (int nt = 0; nt < 4; ++nt){
          short8 bv0 = *(const short8*)((char*)vt + swz(32 * nt + l31, 2 * (2 * mt + 0) + q5));
          oacc[nt] = MF(pf0, bv0, oacc[nt]);
          short8 bv1 = *(const short8*)((char*)vt + swz(32 * nt + l31, 2 * (2 * mt + 1) + q5));
          oacc[nt] = MF(pf1, bv1, oacc[nt]);
        }
      }
    }

    // ---- pair merge: oacc(w) += oacc(w+8), ls likewise; khL+vt reused as scratch
    __syncthreads();                   // all khL/vt/hL reads done
    if (w >= 8) lsx[w - 8][lane] = ls_tot;
#pragma unroll 1
    for (int rnd = 0; rnd < 2; ++rnd){
      if (w >= 8 + 4 * rnd && w < 12 + 4 * rnd){
        char* bp = (char*)mslot(khL, vt, w - 8 - 4 * rnd) + lane * 256;
#pragma unroll
        for (int ci = 0; ci < 16; ++ci){
          f32x4 t;
          t[0] = oacc[ci >> 2][4 * (ci & 3) + 0];
          t[1] = oacc[ci >> 2][4 * (ci & 3) + 1];
          t[2] = oacc[ci >> 2][4 * (ci & 3) + 2];
          t[3] = oacc[ci >> 2][4 * (ci & 3) + 3];
          *(f32x4*)(bp + ((ci ^ (lane & 15)) << 4)) = t;
        }
      }
      __syncthreads();
      if (w >= 4 * rnd && w < 4 + 4 * rnd){
        char* bp = (char*)mslot(khL, vt, w - 4 * rnd) + lane * 256;
#pragma unroll
        for (int ci = 0; ci < 16; ++ci){
          f32x4 t = *(const f32x4*)(bp + ((ci ^ (lane & 15)) << 4));
          oacc[ci >> 2][4 * (ci & 3) + 0] += t[0];
          oacc[ci >> 2][4 * (ci & 3) + 1] += t[1];
          oacc[ci >> 2][4 * (ci & 3) + 2] += t[2];
          oacc[ci >> 2][4 * (ci & 3) + 3] += t[3];
        }
      }
      __syncthreads();                 // slot reuse (rnd 0) / merge complete (rnd 1)
    }

    // ---- epilogue (waves 0..7 own merged oacc): /l, +residual, LN, write hL
    if (w < 8){
      ls_tot += lsx[w][lane];
      float l_run = ls_tot + __shfl_xor(ls_tot, 32);
      float linv = 1.f / l_run;
      float gv[4], bbv[4];
#pragma unroll
      for (int nt = 0; nt < 4; ++nt){
        gv[nt]  = ldf(lng, (size_t)li * 128 + 32 * nt + l31, fl);
        bbv[nt] = ldf(lnb, (size_t)li * 128 + 32 * nt + l31, fl);
      }
#pragma unroll
      for (int reg = 0; reg < 16; ++reg){
        int rr = (reg & 3) + 8 * (reg >> 2) + 4 * q5;
        int srow = 32 * sg + rr;
        float lrv = __shfl(linv, rr);
        float s1 = 0.f, s2 = 0.f;
#pragma unroll
        for (int nt = 0; nt < 4; ++nt){
          int d = 32 * nt + l31;
          float res = b2f(*(const u16*)((char*)hL + swz(srow, d >> 3) + (d & 7) * 2));
          float v = oacc[nt][reg] * lrv + res;
          oacc[nt][reg] = v;
          s1 += v; s2 += v * v;
        }
#pragma unroll
        for (int off = 1; off < 32; off <<= 1){ s1 += __shfl_xor(s1, off); s2 += __shfl_xor(s2, off); }
        float mu = s1 * 0.0078125f;
        float rs = rsqrtf(fmaxf(s2 * 0.0078125f - mu * mu, 0.f) + 1e-5f);
#pragma unroll
        for (int nt = 0; nt < 4; ++nt){
          int d = 32 * nt + l31;
          float v = (oacc[nt][reg] - mu) * rs * gv[nt] + bbv[nt];
          *(u16*)((char*)hL + swz(srow, d >> 3) + (d & 7) * 2) = f2b(v);
        }
      }
    }
    __syncthreads();                   // hL update visible before next layer / store
  }

  // final h -> global, coalesced 16B chunks
#pragma unroll
  for (int it = 0; it < 4; ++it){
    int c = it * 1024 + tid, row = c >> 4, ch = c & 15;
    *(short8*)(hgq + (size_t)bl * 32768 + row * 128 + ch * 8) =
        *(const short8*)((char*)hL + swz(row, ch));
  }
}

// ---------------- MLP head ----------------

__global__ __launch_bounds__(256) void k_mlp1(const u16* se, const u16* hgq, const u16* h1WT,
                                              float* part, int qoff, int nb){
  int mb = blockIdx.x, ks = blockIdx.y;
  int tid = threadIdx.x, w = tid >> 6, lane = tid & 63, l31 = lane & 31, q5 = lane >> 5;
  int b0 = mb * 32;
  floatx16 acc = fz();
  const u16* brow = h1WT + (size_t)(32 * w + l31) * 32896;
  int br = b0 + l31;
  const u16* seb = se + (size_t)(qoff + br) * 128;
  const u16* hb = hgq + (size_t)br * 32768;
  for (int kk = 0; kk < 257; ++kk){
    int kbase = ks * 4112 + kk * 16;
    const u16* ap = (kbase < 128) ? (seb + kbase + q5 * 8) : (hb + (kbase - 128) + q5 * 8);
    short8 a = *(const short8*)ap;
    short8 bf = *(const short8*)(brow + kbase + q5 * 8);
    acc = MF(a, bf, acc);
  }
#pragma unroll
  for (int reg = 0; reg < 16; ++reg){
    int rr = (reg & 3) + 8 * (reg >> 2) + 4 * q5;
    part[(size_t)ks * nb * 128 + (size_t)(b0 + rr) * 128 + 32 * w + l31] = acc[reg];
  }
}

__global__ __launch_bounds__(256) void k_mlp1red(const float* part, const u16* h1b, float* z1q,
                                                 const int* dflag, int nb){
  int fl = dflag[0];
  int idx = blockIdx.x * 256 + threadIdx.x;    // 0..nb*128-1
  float s = ldf(h1b, idx & 127, fl);
  size_t stride = (size_t)nb * 128;
#pragma unroll
  for (int ks = 0; ks < 8; ++ks) s += part[(size_t)ks * stride + idx];
  z1q[idx] = fmaxf(s, 0.f);
}

__global__ __launch_bounds__(256) void k_mlp2(const float* z1, const u16* h2W, const u16* h2b,
                                              float* z2, const int* dflag){
  int fl = dflag[0];
  int idx = blockIdx.x * 256 + threadIdx.x;    // 0..131071
  int b = idx >> 6, j = idx & 63;
  float s = ldf(h2b, j, fl);
  const float* zr = z1 + (size_t)b * 128;
  for (int k = 0; k < 128; ++k) s += zr[k] * ldf(h2W, (size_t)k * 64 + j, fl);
  z2[idx] = fmaxf(s, 0.f);
}

__global__ __launch_bounds__(256) void k_mlp3(const float* z2, const u16* h3W, const u16* h3b,
                                              void* out, const int* dflag){
  int fl = dflag[0];
  int b = blockIdx.x * 256 + threadIdx.x;      // 0..2047
  float s = ldf(h3b, 0, fl);
  const float* zr = z2 + (size_t)b * 64;
#pragma unroll
  for (int j = 0; j < 64; ++j) s += zr[j] * ldf(h3W, j, fl);
  if (!__builtin_isfinite(s)) s = 0.f;
  if (fl) ((float*)out)[b] = s;
  else    ((u16*)out)[b] = f2b(s);
}

// ---------------- launch ----------------

extern "C" void kernel_launch(void* const* d_in, const int* in_sizes, int n_in,
                              void* d_out, int out_size, void* d_ws, size_t ws_size,
                              hipStream_t stream) {
  const u16* x   = (const u16*)d_in[0];
  const u16* sW  = (const u16*)d_in[1];
  const u16* sb  = (const u16*)d_in[2];
  const u16* hW  = (const u16*)d_in[3];
  const u16* hb  = (const u16*)d_in[4];
  const u16* qW  = (const u16*)d_in[5];
  const u16* qb  = (const u16*)d_in[6];
  const u16* kW  = (const u16*)d_in[7];
  // d_in[8] = kb : cancels in softmax, unused
  const u16* vW  = (const u16*)d_in[9];
  const u16* vb  = (const u16*)d_in[10];
  const u16* lng = (const u16*)d_in[11];
  const u16* lnb = (const u16*)d_in[12];
  const u16* h1W = (const u16*)d_in[13];
  const u16* h1b = (const u16*)d_in[14];
  const u16* h2W = (const u16*)d_in[15];
  const u16* h2b = (const u16*)d_in[16];
  const u16* h3W = (const u16*)d_in[17];
  const u16* h3b = (const u16*)d_in[18];

  // full-pass mode (r5-r8 ran this branch); quarter mode fallback.
  const int nb = (ws_size >= 153600000ull) ? 2048 : 512;
  const int nq = 2048 / nb;

  char* W = (char*)d_ws;
  size_t o = 0;
  u16*   hg    = (u16*)(W + o); o += (size_t)nb * 65536;   // nb*32768*2
  u16*   h1WT  = (u16*)(W + o); o += 8421376;
  u16*   se    = (u16*)(W + o); o += 524288;               // always full 2048x128 bf16
  u16*   Mrow  = (u16*)(W + o); o += 65536;
  u16*   vWT   = (u16*)(W + o); o += 65536;
  float* uv    = (float*)(W + o); o += 1024;
  float* part  = (float*)(W + o); o += (size_t)nb * 4096;  // 8 * nb*128 * 4B
  float* z1    = (float*)(W + o); o += 1048576;            // always full
  float* z2    = (float*)(W + o); o += 524288;
  int*   dflag = (int*)(W + o);

  k_detect<<<1, 256, 0, stream>>>(x, dflag);
  k_prepw<<<256, 128, 0, stream>>>(qW, kW, vW, qb, Mrow, vWT, uv, dflag);
  k_h1t<<<514, 256, 0, stream>>>(h1W, h1WT, dflag);

  for (int q = 0; q < nq; ++q){
    int qoff = q * nb;
    k_fan<<<nb, 1024, 0, stream>>>(x, sW, sb, hW, hb, Mrow, uv, vWT, vb,
                                   lng, lnb, hg, se, qoff, dflag);
    k_mlp1<<<dim3(nb / 32, 8), 256, 0, stream>>>(se, hg, h1WT, part, qoff, nb);
    k_mlp1red<<<nb / 2, 256, 0, stream>>>(part, h1b, z1 + (size_t)qoff * 128, dflag, nb);
  }

  k_mlp2<<<512, 256, 0, stream>>>(z1, h2W, h2b, z2, dflag);
  k_mlp3<<<8, 256, 0, stream>>>(z2, h3W, h3b, d_out, dflag);
}

// Round 3
// 1508.663 us; speedup vs baseline: 1.0833x; 1.0811x over previous
//
#include <hip/hip_runtime.h>
#include <cstddef>

// FAN_39273180955145 — round 13. r11/r12 post-mortem: at 1024 threads the
// per-thread budget is hard-capped at 128 regs (16 waves must co-reside on
// one CU); accum demand of the mt-split design (oacc[4]=64 + sa16 + tile 16)
// left only 64 arch regs (the reported VGPR_Count) -> ~2.3GB scratch spill.
// launch_bounds(,4) was a no-op (already implied). Fix: pair-split by nt
// (output columns) instead of mt:
//  * oacc[2] (32 regs) per wave -> accum peak ~48, arch ~80: fits 128.
//  * scores+exp duplicated across pair (only duplicated phase); kh/v tiles,
//    PV, c_all, embed, epilogue stay halved vs r10; 4 waves/SIMD kept.
//  * oacc merge machinery deleted (no mslot/lsx, 4 fewer barriers); ls needs
//    no exchange (pair computes identical row sums); LN s1/s2 partials
//    exchanged via 4KB sxe buffer.
// Math identical to r8/r10 (passed, absmax 9.8e-4).

typedef unsigned short u16;
typedef unsigned int u32;
typedef short short8 __attribute__((ext_vector_type(8)));
typedef u32 u32x2 __attribute__((ext_vector_type(2)));
typedef float floatx16 __attribute__((ext_vector_type(16)));

__device__ __forceinline__ float b2f(u16 u){ return __uint_as_float(((u32)u) << 16); }
__device__ __forceinline__ u16 f2b(float f){
  u32 u = __float_as_uint(f);
  return (u16)((u + 0x7fffu + ((u >> 16) & 1u)) >> 16);
}
// flagged input load: f32 ? fp32 : bf16; non-finite -> 0
__device__ __forceinline__ float ldf(const u16* p, size_t i, int f32){
  float v = f32 ? ((const float*)p)[i] : b2f(p[i]);
  return __builtin_isfinite(v) ? v : 0.f;
}
__device__ __forceinline__ u32 pk2(float a, float b){
  return ((u32)f2b(b) << 16) | (u32)f2b(a);
}
// [rows][128 bf16] LDS region, 256B rows, 16B-chunk xor swizzle (2-way max = free)
__device__ __forceinline__ int swz(int row, int ch){ return (row << 8) | ((ch ^ (row & 15)) << 4); }
__device__ __forceinline__ floatx16 fz(){
  floatx16 z;
#pragma unroll
  for (int i = 0; i < 16; ++i) z[i] = 0.f;
  return z;
}
__device__ __forceinline__ floatx16 MF(short8 a, short8 b, floatx16 c){
  return __builtin_amdgcn_mfma_f32_32x32x16_bf16(a, b, c, 0, 0, 0);
}
// C-layout 32x32 tile (by value) -> k-chunk A-fragment via xor-32 exchange (r4-verified).
__device__ __forceinline__ short8 frag_from(floatx16 cv, int half, int q5){
  int r0 = half * 8;
  u32 e01 = pk2(cv[r0 + 0], cv[r0 + 1]);
  u32 e23 = pk2(cv[r0 + 2], cv[r0 + 3]);
  u32 o01 = pk2(cv[r0 + 4], cv[r0 + 5]);
  u32 o23 = pk2(cv[r0 + 6], cv[r0 + 7]);
  u32 s0 = q5 ? e01 : o01;
  u32 s1 = q5 ? e23 : o23;
  u32 r0v = __shfl_xor(s0, 32);
  u32 r1v = __shfl_xor(s1, 32);
  union { u32 u[4]; short8 v; } un;
  un.u[0] = q5 ? r0v : e01;
  un.u[1] = q5 ? r1v : e23;
  un.u[2] = q5 ? o01 : r0v;
  un.u[3] = q5 ? o23 : r1v;
  return un.v;
}

// ---------------- dtype detector (r4-verified) ----------------
__global__ __launch_bounds__(256) void k_detect(const u16* x, int* dflag){
  __shared__ int red[256];
  int t = threadIdx.x, cnt = 0;
  for (int i = t; i < 4096; i += 256){
    u16 v = x[2 * i];
    int e = (v >> 7) & 0xFF;
    if (e == 0xFF || e >= 0x90 || (e > 0 && e <= 0x20)) ++cnt;
  }
  red[t] = cnt;
  __syncthreads();
  for (int off = 128; off > 0; off >>= 1){
    if (t < off) red[t] += red[t + off];
    __syncthreads();
  }
  if (t == 0) dflag[0] = (red[0] > 1000) ? 1 : 0;
}

// ---------------- prep kernels ----------------

// Mrow[r][c] = M'[r,c] (row-major, kh A-operand); vWT[d][e] = vW[e][d]; uv = u'.
__global__ __launch_bounds__(128) void k_prepw(const u16* qW, const u16* kW, const u16* vW,
                                               const u16* qb, u16* Mrow, u16* vWT, float* uv,
                                               const int* dflag){
  int fl = dflag[0];
  int i = blockIdx.x >> 7, f = blockIdx.x & 127, e = threadIdx.x;
  size_t qo = (size_t)(i * 128 + e) * 128;   // qW row e
  size_t ko = (size_t)(i * 128 + f) * 128;   // kW row f
  float m = 0.f;
  for (int d = 0; d < 128; ++d) m += ldf(qW, qo + d, fl) * ldf(kW, ko + d, fl);
  const float RS = 0.08838834764831845f;  // 1/sqrt(128)
  Mrow[(i * 128 + e) * 128 + f] = f2b(m * RS);                // M'[e,f] at [e][f]
  vWT[(i * 128 + f) * 128 + e] = f2b(ldf(vW, qo + f, fl));    // vWT[d][e] = vW[e][d]
  __shared__ float red[128];
  red[e] = ldf(kW, ko + e, fl) * ldf(qb, (size_t)i * 128 + e, fl);
  __syncthreads();
  for (int off = 64; off > 0; off >>= 1){
    if (e < off) red[e] += red[e + off];
    __syncthreads();
  }
  if (e == 0) uv[i * 128 + f] = red[0] * RS;
}

__global__ __launch_bounds__(256) void k_h1t(const u16* h1W, u16* h1WT, const int* dflag){
  int fl = dflag[0];
  __shared__ u16 tile[64][130];
  int k0 = blockIdx.x * 64, tid = threadIdx.x;
#pragma unroll 4
  for (int it = 0; it < 32; ++it){
    int r = it * 2 + (tid >> 7), c = tid & 127;
    tile[r][c] = f2b(ldf(h1W, (size_t)(k0 + r) * 128 + c, fl));
  }
  __syncthreads();
#pragma unroll 4
  for (int it = 0; it < 32; ++it){
    int idx = it * 256 + tid, n = idx >> 6, kk = idx & 63;
    h1WT[(size_t)n * 32896 + k0 + kk] = tile[kk][n];
  }
}

// -------- fused embed + 2 attention layers; h in LDS; one block = one batch --------
// 1024 threads = 16 waves (4/SIMD). Wave pair (w, w+8) shares score-group w&7;
// pair splits output columns: wave handles nt quadrants {2*mh, 2*mh+1}.

__global__ __launch_bounds__(1024, 4) void k_fan(
    const u16* x, const u16* sW, const u16* sb, const u16* hW, const u16* hbe,
    const u16* Mrow, const float* uv, const u16* vWT, const u16* vb,
    const u16* lng, const u16* lnb,
    u16* hgq, u16* se, int qoff, const int* dflag){
  __shared__ alignas(16) u16 hL[32768];    // h   [256 s][128 f], swz, 64KB
  __shared__ alignas(16) u16 vt[16384];    // vT  [128 d][128 t], swz, 32KB
  __shared__ alignas(16) u16 khL[16384];   // kh  [128 t][128 f], swz, 32KB
  __shared__ float c_all[256];             // c_t, whole layer
  __shared__ float u_lds[128];             // u' for current layer
  __shared__ float sxe[2][2][8][32];       // LN partial {s1,s2}[mh][sg][row], 4KB
  int fl = dflag[0];
  int bl = blockIdx.x;
  int b = qoff + bl;
  int tid = threadIdx.x, w = tid >> 6, lane = tid & 63, l31 = lane & 31, q5 = lane >> 5;
  size_t xo = (size_t)b * 272;
  const float LKOFF = -20.72326584f;       // ln(1e-9); off-diag log-kernel value

  // scalar embedding (lanes 0..127)
  if (tid < 128){
    float acc = ldf(sb, tid, fl);
#pragma unroll
    for (int j = 0; j < 16; ++j) acc += ldf(x, xo + j, fl) * ldf(sW, (size_t)j * 128 + tid, fl);
    se[(size_t)b * 128 + tid] = f2b(acc);
  }
  // history embedding -> hL (4096 16B chunks over 1024 threads)
#pragma unroll
  for (int it = 0; it < 4; ++it){
    int c = it * 1024 + tid, s = c >> 4, ch = c & 15;
    float xv = ldf(x, xo + 16 + s, fl);
    short8 r;
#pragma unroll
    for (int j = 0; j < 8; ++j)
      r[j] = (short)f2b(xv * ldf(hW, ch * 8 + j, fl) + ldf(hbe, ch * 8 + j, fl));
    *(short8*)((char*)hL + swz(s, ch)) = r;
  }

#pragma unroll 1
  for (int li = 0; li < 2; ++li){
    const u16* Mri  = Mrow + li * 16384;
    const u16* vWTi = vWT + li * 16384;
    if (tid < 128) u_lds[tid] = uv[li * 128 + tid];
    __syncthreads();                 // hL (embed/prev epilogue) + u_lds visible

    // ---- c_all[t] = u'.h_t; 16 waves x 16 rows, 4 lanes per row (k-quarters)
    {
      int row = 16 * w + (lane & 15);
      int kq = lane >> 4;            // 0..3
      float dot = 0.f;
#pragma unroll
      for (int kc = 0; kc < 4; ++kc){
        int ch = 4 * kc + kq;
        short8 hv = *(const short8*)((char*)hL + swz(row, ch));
#pragma unroll
        for (int j = 0; j < 8; ++j) dot += u_lds[ch * 8 + j] * b2f(hv[j]);
      }
      dot += __shfl_xor(dot, 16);
      dot += __shfl_xor(dot, 32);
      if (kq == 0) c_all[row] = dot;
    }

    float ls_tot = 0.f;
    floatx16 oacc[2];
#pragma unroll
    for (int j = 0; j < 2; ++j) oacc[j] = fz();
    int sg = w & 7, mh = w >> 3;
    int scol = 32 * sg + l31;

#pragma unroll 1
    for (int tt = 0; tt < 2; ++tt){
      int t0 = tt * 128;
      __syncthreads();               // prior tile's khL/vt reads done; c_all visible
      // ---- kh-tile: khL[t][f] = sum_e M'[f,e] h[t0+t][e]; 16 units -> 1/wave
      {
        int mtv = w & 3, ntv = w >> 2;
        floatx16 ka = fz();
#pragma unroll 2
        for (int kc = 0; kc < 8; ++kc){
          short8 av = *(const short8*)(Mri + (32 * mtv + l31) * 128 + kc * 16 + q5 * 8);
          short8 bh = *(const short8*)((char*)hL + swz(t0 + 32 * ntv + l31, 2 * kc + q5));
          ka = MF(av, bh, ka);
        }
        int tloc = 32 * ntv + l31;
#pragma unroll
        for (int qd = 0; qd < 4; ++qd){
          // regs 4qd..4qd+3 -> frow = 32mtv + 8qd + 4q5 + (0..3): one 16B chunk
          u32x2 pv;
          pv.x = pk2(ka[4 * qd + 0], ka[4 * qd + 1]);
          pv.y = pk2(ka[4 * qd + 2], ka[4 * qd + 3]);
          *(u32x2*)((char*)khL + swz(tloc, 4 * mtv + qd) + 8 * q5) = pv;
        }
      }
      // ---- v-tile: vt[d][t] = sum_e vWT[d][e] h[t0+t][e] + vb[d]; 16 units -> 1/wave
      {
        int mtv = w & 3, ntv = w >> 2;
        float vbl = ldf(vb, (size_t)li * 128 + 32 * mtv + l31, fl);
        floatx16 va = fz();
#pragma unroll 2
        for (int kc = 0; kc < 8; ++kc){
          short8 av = *(const short8*)(vWTi + (32 * mtv + l31) * 128 + kc * 16 + q5 * 8);
          short8 bh = *(const short8*)((char*)hL + swz(t0 + 32 * ntv + l31, 2 * kc + q5));
          va = MF(av, bh, va);
        }
#pragma unroll
        for (int reg = 0; reg < 16; ++reg){
          int rr = (reg & 3) + 8 * (reg >> 2) + 4 * q5;
          int tloc = 32 * ntv + l31;
          *(u16*)((char*)vt + swz(32 * mtv + rr, tloc >> 3) + (tloc & 7) * 2) =
              f2b(va[reg] + __shfl(vbl, rr));
        }
      }
      __syncthreads();               // khL, vt complete
      // ---- scores + exp + P@V; full mt range per wave (pair duplicates exp),
      //      PV only for own nt quadrants {2mh, 2mh+1}
#pragma unroll 1
      for (int mt = 0; mt < 4; ++mt){
        floatx16 sa = fz();
#pragma unroll 2
        for (int kc = 0; kc < 8; ++kc){
          short8 ak = *(const short8*)((char*)khL + swz(32 * mt + l31, 2 * kc + q5));
          short8 bq = *(const short8*)((char*)hL + swz(32 * sg + l31, 2 * kc + q5));
          sa = MF(ak, bq, sa);
        }
#pragma unroll
        for (int reg = 0; reg < 16; ++reg){
          int trl = 32 * mt + (reg & 3) + 8 * (reg >> 2) + 4 * q5;
          int tg = t0 + trl;
          float lk = (tg == scol) ? 0.f : LKOFF;
          float v = sa[reg] + c_all[tg] + lk;
          v = fminf(fmaxf(v, -50.f), 50.f);
          float p = __expf(v - 8.f);   // fixed max: softmax shift-invariant
          sa[reg] = p;
          ls_tot += p;
        }
        // pf frags computed BEFORE the bv loads so sa dies here (register diet)
        short8 pf0 = frag_from(sa, 0, q5);
        short8 pf1 = frag_from(sa, 1, q5);
#pragma unroll
        for (int j = 0; j < 2; ++j){
          int nt = 2 * mh + j;
          short8 bv0 = *(const short8*)((char*)vt + swz(32 * nt + l31, 2 * (2 * mt + 0) + q5));
          oacc[j] = MF(pf0, bv0, oacc[j]);
          short8 bv1 = *(const short8*)((char*)vt + swz(32 * nt + l31, 2 * (2 * mt + 1) + q5));
          oacc[j] = MF(pf1, bv1, oacc[j]);
        }
      }
    }

    // ---- epilogue (all 16 waves): /l, +residual, LN partials, exchange, write hL
    __syncthreads();                   // all khL/vt/hL reads done
    float l_run = ls_tot + __shfl_xor(ls_tot, 32);
    float linv = 1.f / l_run;
    float gv[2], bbv[2];
#pragma unroll
    for (int j = 0; j < 2; ++j){
      int nt = 2 * mh + j;
      gv[j]  = ldf(lng, (size_t)li * 128 + 32 * nt + l31, fl);
      bbv[j] = ldf(lnb, (size_t)li * 128 + 32 * nt + l31, fl);
    }
    // pass 1: residual add (own quadrants), partial s1/s2 per row -> sxe
#pragma unroll
    for (int reg = 0; reg < 16; ++reg){
      int rr = (reg & 3) + 8 * (reg >> 2) + 4 * q5;
      int srow = 32 * sg + rr;
      float lrv = __shfl(linv, rr);
      float s1 = 0.f, s2 = 0.f;
#pragma unroll
      for (int j = 0; j < 2; ++j){
        int d = 32 * (2 * mh + j) + l31;
        float res = b2f(*(const u16*)((char*)hL + swz(srow, d >> 3) + (d & 7) * 2));
        float v = oacc[j][reg] * lrv + res;
        oacc[j][reg] = v;
        s1 += v; s2 += v * v;
      }
#pragma unroll
      for (int off = 1; off < 32; off <<= 1){ s1 += __shfl_xor(s1, off); s2 += __shfl_xor(s2, off); }
      if (l31 == 0){ sxe[0][mh][sg][rr] = s1; sxe[1][mh][sg][rr] = s2; }
    }
    __syncthreads();                   // sxe complete
    // pass 2: total stats, normalize, write own quadrants back to hL
#pragma unroll
    for (int reg = 0; reg < 16; ++reg){
      int rr = (reg & 3) + 8 * (reg >> 2) + 4 * q5;
      int srow = 32 * sg + rr;
      float s1 = sxe[0][0][sg][rr] + sxe[0][1][sg][rr];
      float s2 = sxe[1][0][sg][rr] + sxe[1][1][sg][rr];
      float mu = s1 * 0.0078125f;
      float rs = rsqrtf(fmaxf(s2 * 0.0078125f - mu * mu, 0.f) + 1e-5f);
#pragma unroll
      for (int j = 0; j < 2; ++j){
        int d = 32 * (2 * mh + j) + l31;
        float v = (oacc[j][reg] - mu) * rs * gv[j] + bbv[j];
        *(u16*)((char*)hL + swz(srow, d >> 3) + (d & 7) * 2) = f2b(v);
      }
    }
    __syncthreads();                   // hL update visible before next layer / store
  }

  // final h -> global, coalesced 16B chunks
#pragma unroll
  for (int it = 0; it < 4; ++it){
    int c = it * 1024 + tid, row = c >> 4, ch = c & 15;
    *(short8*)(hgq + (size_t)bl * 32768 + row * 128 + ch * 8) =
        *(const short8*)((char*)hL + swz(row, ch));
  }
}

// ---------------- MLP head ----------------

__global__ __launch_bounds__(256) void k_mlp1(const u16* se, const u16* hgq, const u16* h1WT,
                                              float* part, int qoff, int nb){
  int mb = blockIdx.x, ks = blockIdx.y;
  int tid = threadIdx.x, w = tid >> 6, lane = tid & 63, l31 = lane & 31, q5 = lane >> 5;
  int b0 = mb * 32;
  floatx16 acc = fz();
  const u16* brow = h1WT + (size_t)(32 * w + l31) * 32896;
  int br = b0 + l31;
  const u16* seb = se + (size_t)(qoff + br) * 128;
  const u16* hb = hgq + (size_t)br * 32768;
  for (int kk = 0; kk < 257; ++kk){
    int kbase = ks * 4112 + kk * 16;
    const u16* ap = (kbase < 128) ? (seb + kbase + q5 * 8) : (hb + (kbase - 128) + q5 * 8);
    short8 a = *(const short8*)ap;
    short8 bf = *(const short8*)(brow + kbase + q5 * 8);
    acc = MF(a, bf, acc);
  }
#pragma unroll
  for (int reg = 0; reg < 16; ++reg){
    int rr = (reg & 3) + 8 * (reg >> 2) + 4 * q5;
    part[(size_t)ks * nb * 128 + (size_t)(b0 + rr) * 128 + 32 * w + l31] = acc[reg];
  }
}

__global__ __launch_bounds__(256) void k_mlp1red(const float* part, const u16* h1b, float* z1q,
                                                 const int* dflag, int nb){
  int fl = dflag[0];
  int idx = blockIdx.x * 256 + threadIdx.x;    // 0..nb*128-1
  float s = ldf(h1b, idx & 127, fl);
  size_t stride = (size_t)nb * 128;
#pragma unroll
  for (int ks = 0; ks < 8; ++ks) s += part[(size_t)ks * stride + idx];
  z1q[idx] = fmaxf(s, 0.f);
}

__global__ __launch_bounds__(256) void k_mlp2(const float* z1, const u16* h2W, const u16* h2b,
                                              float* z2, const int* dflag){
  int fl = dflag[0];
  int idx = blockIdx.x * 256 + threadIdx.x;    // 0..131071
  int b = idx >> 6, j = idx & 63;
  float s = ldf(h2b, j, fl);
  const float* zr = z1 + (size_t)b * 128;
  for (int k = 0; k < 128; ++k) s += zr[k] * ldf(h2W, (size_t)k * 64 + j, fl);
  z2[idx] = fmaxf(s, 0.f);
}

__global__ __launch_bounds__(256) void k_mlp3(const float* z2, const u16* h3W, const u16* h3b,
                                              void* out, const int* dflag){
  int fl = dflag[0];
  int b = blockIdx.x * 256 + threadIdx.x;      // 0..2047
  float s = ldf(h3b, 0, fl);
  const float* zr = z2 + (size_t)b * 64;
#pragma unroll
  for (int j = 0; j < 64; ++j) s += zr[j] * ldf(h3W, j, fl);
  if (!__builtin_isfinite(s)) s = 0.f;
  if (fl) ((float*)out)[b] = s;
  else    ((u16*)out)[b] = f2b(s);
}

// ---------------- launch ----------------

extern "C" void kernel_launch(void* const* d_in, const int* in_sizes, int n_in,
                              void* d_out, int out_size, void* d_ws, size_t ws_size,
                              hipStream_t stream) {
  const u16* x   = (const u16*)d_in[0];
  const u16* sW  = (const u16*)d_in[1];
  const u16* sb  = (const u16*)d_in[2];
  const u16* hW  = (const u16*)d_in[3];
  const u16* hb  = (const u16*)d_in[4];
  const u16* qW  = (const u16*)d_in[5];
  const u16* qb  = (const u16*)d_in[6];
  const u16* kW  = (const u16*)d_in[7];
  // d_in[8] = kb : cancels in softmax, unused
  const u16* vW  = (const u16*)d_in[9];
  const u16* vb  = (const u16*)d_in[10];
  const u16* lng = (const u16*)d_in[11];
  const u16* lnb = (const u16*)d_in[12];
  const u16* h1W = (const u16*)d_in[13];
  const u16* h1b = (const u16*)d_in[14];
  const u16* h2W = (const u16*)d_in[15];
  const u16* h2b = (const u16*)d_in[16];
  const u16* h3W = (const u16*)d_in[17];
  const u16* h3b = (const u16*)d_in[18];

  // full-pass mode (r5-r8 ran this branch); quarter mode fallback.
  const int nb = (ws_size >= 153600000ull) ? 2048 : 512;
  const int nq = 2048 / nb;

  char* W = (char*)d_ws;
  size_t o = 0;
  u16*   hg    = (u16*)(W + o); o += (size_t)nb * 65536;   // nb*32768*2
  u16*   h1WT  = (u16*)(W + o); o += 8421376;
  u16*   se    = (u16*)(W + o); o += 524288;               // always full 2048x128 bf16
  u16*   Mrow  = (u16*)(W + o); o += 65536;
  u16*   vWT   = (u16*)(W + o); o += 65536;
  float* uv    = (float*)(W + o); o += 1024;
  float* part  = (float*)(W + o); o += (size_t)nb * 4096;  // 8 * nb*128 * 4B
  float* z1    = (float*)(W + o); o += 1048576;            // always full
  float* z2    = (float*)(W + o); o += 524288;
  int*   dflag = (int*)(W + o);

  k_detect<<<1, 256, 0, stream>>>(x, dflag);
  k_prepw<<<256, 128, 0, stream>>>(qW, kW, vW, qb, Mrow, vWT, uv, dflag);
  k_h1t<<<514, 256, 0, stream>>>(h1W, h1WT, dflag);

  for (int q = 0; q < nq; ++q){
    int qoff = q * nb;
    k_fan<<<nb, 1024, 0, stream>>>(x, sW, sb, hW, hb, Mrow, uv, vWT, vb,
                                   lng, lnb, hg, se, qoff, dflag);
    k_mlp1<<<dim3(nb / 32, 8), 256, 0, stream>>>(se, hg, h1WT, part, qoff, nb);
    k_mlp1red<<<nb / 2, 256, 0, stream>>>(part, h1b, z1 + (size_t)qoff * 128, dflag, nb);
  }

  k_mlp2<<<512, 256, 0, stream>>>(z1, h2W, h2b, z2, dflag);
  k_mlp3<<<8, 256, 0, stream>>>(z2, h3W, h3b, d_out, dflag);
}

// Round 4
// 1072.571 us; speedup vs baseline: 1.5237x; 1.4066x over previous
//
#include <hip/hip_runtime.h>
#include <cstddef>

// FAN_39273180955145 — round 14. r11-r13 post-mortem: 1024-thread blocks cap
// the unified reg file at 128/thread (64 arch + 64 accum, rocprof shows arch
// only) -> structural spill (r13 still 0.6GB scratch writes). Revert to the
// proven 512-thread / 256-reg structure (r10, 921us, spill-free) and attack
// its latency (VALUBusy 33, MfmaUtil 9.4, all pipes idle) with ILP instead:
//  * kh+v phases MERGED: one bh read feeds 4 independent MFMA chains
//    (ka0/ka1/va0/va1) -> half the hL reads, 4x chain ILP.
//  * v operand swap MF(bh,av): D[t][d] reg->t, lane->d -> packed b64 vt
//    stores + lane-local bias; deletes 32 ds_write_u16 + 32 shfl per
//    wave/tile (source of the constant 2.1M bank conflicts).
//  * scores: q-fragments hoisted per tt (bqr[8], reused over 4 mt); sa split
//    into even/odd kc chains (halves dependent-MFMA path); setprio around
//    MFMA clusters.
//  * __launch_bounds__(512, 2) pins the 256-reg budget.
// Math identical to r8/r10 (passed, absmax 9.8e-4): S[s,t]=sum_f h[s,f]kh[t,f]
// +c_t, kh[t,f]=sum_e M'[f,e]h[t,e]; analytic 2-value log-kernel; fixed-max
// softmax p=exp(s-8); dtype detector; h in LDS; 1 block = 1 batch.

typedef unsigned short u16;
typedef unsigned int u32;
typedef short short8 __attribute__((ext_vector_type(8)));
typedef u32 u32x2 __attribute__((ext_vector_type(2)));
typedef float floatx16 __attribute__((ext_vector_type(16)));

__device__ __forceinline__ float b2f(u16 u){ return __uint_as_float(((u32)u) << 16); }
__device__ __forceinline__ u16 f2b(float f){
  u32 u = __float_as_uint(f);
  return (u16)((u + 0x7fffu + ((u >> 16) & 1u)) >> 16);
}
// flagged input load: f32 ? fp32 : bf16; non-finite -> 0
__device__ __forceinline__ float ldf(const u16* p, size_t i, int f32){
  float v = f32 ? ((const float*)p)[i] : b2f(p[i]);
  return __builtin_isfinite(v) ? v : 0.f;
}
__device__ __forceinline__ u32 pk2(float a, float b){
  return ((u32)f2b(b) << 16) | (u32)f2b(a);
}
// [rows][128 bf16] LDS region, 256B rows, 16B-chunk xor swizzle (2-way max = free)
__device__ __forceinline__ int swz(int row, int ch){ return (row << 8) | ((ch ^ (row & 15)) << 4); }
__device__ __forceinline__ floatx16 fz(){
  floatx16 z;
#pragma unroll
  for (int i = 0; i < 16; ++i) z[i] = 0.f;
  return z;
}
__device__ __forceinline__ floatx16 MF(short8 a, short8 b, floatx16 c){
  return __builtin_amdgcn_mfma_f32_32x32x16_bf16(a, b, c, 0, 0, 0);
}
// C-layout 32x32 tile (by value) -> k-chunk A-fragment via xor-32 exchange (r4-verified).
__device__ __forceinline__ short8 frag_from(floatx16 cv, int half, int q5){
  int r0 = half * 8;
  u32 e01 = pk2(cv[r0 + 0], cv[r0 + 1]);
  u32 e23 = pk2(cv[r0 + 2], cv[r0 + 3]);
  u32 o01 = pk2(cv[r0 + 4], cv[r0 + 5]);
  u32 o23 = pk2(cv[r0 + 6], cv[r0 + 7]);
  u32 s0 = q5 ? e01 : o01;
  u32 s1 = q5 ? e23 : o23;
  u32 r0v = __shfl_xor(s0, 32);
  u32 r1v = __shfl_xor(s1, 32);
  union { u32 u[4]; short8 v; } un;
  un.u[0] = q5 ? r0v : e01;
  un.u[1] = q5 ? r1v : e23;
  un.u[2] = q5 ? o01 : r0v;
  un.u[3] = q5 ? o23 : r1v;
  return un.v;
}

// ---------------- dtype detector (r4-verified) ----------------
__global__ __launch_bounds__(256) void k_detect(const u16* x, int* dflag){
  __shared__ int red[256];
  int t = threadIdx.x, cnt = 0;
  for (int i = t; i < 4096; i += 256){
    u16 v = x[2 * i];
    int e = (v >> 7) & 0xFF;
    if (e == 0xFF || e >= 0x90 || (e > 0 && e <= 0x20)) ++cnt;
  }
  red[t] = cnt;
  __syncthreads();
  for (int off = 128; off > 0; off >>= 1){
    if (t < off) red[t] += red[t + off];
    __syncthreads();
  }
  if (t == 0) dflag[0] = (red[0] > 1000) ? 1 : 0;
}

// ---------------- prep kernels ----------------

// Mrow[r][c] = M'[r,c] (row-major, kh A-operand); vWT[d][e] = vW[e][d]; uv = u'.
__global__ __launch_bounds__(128) void k_prepw(const u16* qW, const u16* kW, const u16* vW,
                                               const u16* qb, u16* Mrow, u16* vWT, float* uv,
                                               const int* dflag){
  int fl = dflag[0];
  int i = blockIdx.x >> 7, f = blockIdx.x & 127, e = threadIdx.x;
  size_t qo = (size_t)(i * 128 + e) * 128;   // qW row e
  size_t ko = (size_t)(i * 128 + f) * 128;   // kW row f
  float m = 0.f;
  for (int d = 0; d < 128; ++d) m += ldf(qW, qo + d, fl) * ldf(kW, ko + d, fl);
  const float RS = 0.08838834764831845f;  // 1/sqrt(128)
  Mrow[(i * 128 + e) * 128 + f] = f2b(m * RS);                // M'[e,f] at [e][f]
  vWT[(i * 128 + f) * 128 + e] = f2b(ldf(vW, qo + f, fl));    // vWT[d][e] = vW[e][d]
  __shared__ float red[128];
  red[e] = ldf(kW, ko + e, fl) * ldf(qb, (size_t)i * 128 + e, fl);
  __syncthreads();
  for (int off = 64; off > 0; off >>= 1){
    if (e < off) red[e] += red[e + off];
    __syncthreads();
  }
  if (e == 0) uv[i * 128 + f] = red[0] * RS;
}

__global__ __launch_bounds__(256) void k_h1t(const u16* h1W, u16* h1WT, const int* dflag){
  int fl = dflag[0];
  __shared__ u16 tile[64][130];
  int k0 = blockIdx.x * 64, tid = threadIdx.x;
#pragma unroll 4
  for (int it = 0; it < 32; ++it){
    int r = it * 2 + (tid >> 7), c = tid & 127;
    tile[r][c] = f2b(ldf(h1W, (size_t)(k0 + r) * 128 + c, fl));
  }
  __syncthreads();
#pragma unroll 4
  for (int it = 0; it < 32; ++it){
    int idx = it * 256 + tid, n = idx >> 6, kk = idx & 63;
    h1WT[(size_t)n * 32896 + k0 + kk] = tile[kk][n];
  }
}

// -------- fused embed + 2 attention layers; h in LDS; one block = one batch --------

__global__ __launch_bounds__(512, 2) void k_fan(
    const u16* x, const u16* sW, const u16* sb, const u16* hW, const u16* hbe,
    const u16* Mrow, const float* uv, const u16* vWT, const u16* vb,
    const u16* lng, const u16* lnb,
    u16* hgq, u16* se, int qoff, const int* dflag){
  __shared__ alignas(16) u16 hL[32768];    // h   [256 s][128 f], swz, 64KB
  __shared__ alignas(16) u16 vt[16384];    // vT  [128 d][128 t], swz, 32KB
  __shared__ alignas(16) u16 khL[16384];   // kh  [128 t][128 f], swz, 32KB
  __shared__ float c_all[256];             // c_t, whole layer
  __shared__ float u_lds[128];             // u' for current layer
  int fl = dflag[0];
  int bl = blockIdx.x;
  int b = qoff + bl;
  int tid = threadIdx.x, w = tid >> 6, lane = tid & 63, l31 = lane & 31, q5 = lane >> 5;
  size_t xo = (size_t)b * 272;
  const float LKOFF = -20.72326584f;       // ln(1e-9); off-diag log-kernel value

  // scalar embedding (lanes 0..127)
  if (tid < 128){
    float acc = ldf(sb, tid, fl);
#pragma unroll
    for (int j = 0; j < 16; ++j) acc += ldf(x, xo + j, fl) * ldf(sW, (size_t)j * 128 + tid, fl);
    se[(size_t)b * 128 + tid] = f2b(acc);
  }
  // history embedding -> hL
#pragma unroll
  for (int it = 0; it < 8; ++it){
    int c = it * 512 + tid, s = c >> 4, ch = c & 15;
    float xv = ldf(x, xo + 16 + s, fl);
    short8 r;
#pragma unroll
    for (int j = 0; j < 8; ++j)
      r[j] = (short)f2b(xv * ldf(hW, ch * 8 + j, fl) + ldf(hbe, ch * 8 + j, fl));
    *(short8*)((char*)hL + swz(s, ch)) = r;
  }

#pragma unroll 1
  for (int li = 0; li < 2; ++li){
    const u16* Mri  = Mrow + li * 16384;
    const u16* vWTi = vWT + li * 16384;
    if (tid < 128) u_lds[tid] = uv[li * 128 + tid];
    __syncthreads();                 // hL (embed/prev epilogue) + u_lds visible

    // ---- c_all[t] = u'.h_t for all 256 rows; MFMA-operand access pattern (2-way, free)
    {
      int row = 32 * w + l31;
      float dot = 0.f;
#pragma unroll 2
      for (int kc = 0; kc < 8; ++kc){
        int ch = 2 * kc + q5;
        short8 hv = *(const short8*)((char*)hL + swz(row, ch));
#pragma unroll
        for (int j = 0; j < 8; ++j) dot += u_lds[ch * 8 + j] * b2f(hv[j]);
      }
      dot += __shfl_xor(dot, 32);
      if (q5 == 0) c_all[row] = dot;
    }

    float ls_tot = 0.f;
    floatx16 oacc[4];
#pragma unroll
    for (int nt = 0; nt < 4; ++nt) oacc[nt] = fz();
    int scol = 32 * w + l31;

#pragma unroll 1
    for (int tt = 0; tt < 2; ++tt){
      int t0 = tt * 128;
      __syncthreads();               // prior tile's khL/vt reads done; c_all visible
      // ---- merged kh + v tile: one bh read feeds 4 independent MFMA chains.
      // kh[t][f] = sum_e M'[f,e] h[t,e]  (A=Mrow rows, B=h rows)
      // v [t][d] = sum_e h[t,e] vW[e,d]  (A=h rows, B=vWT rows -> D[t][d])
      {
        int mtv = w & 3, ntv0 = (w >> 2) * 2;
        const u16* Ma = Mri  + (32 * mtv + l31) * 128 + q5 * 8;
        const u16* Va = vWTi + (32 * mtv + l31) * 128 + q5 * 8;
        float vbl = ldf(vb, (size_t)li * 128 + 32 * mtv + l31, fl);
        int r0 = t0 + 32 * ntv0 + l31, r1 = r0 + 32;
        floatx16 ka0 = fz(), ka1 = fz(), va0 = fz(), va1 = fz();
#pragma unroll 2
        for (int kc = 0; kc < 8; ++kc){
          short8 avM = *(const short8*)(Ma + kc * 16);
          short8 avV = *(const short8*)(Va + kc * 16);
          short8 bh0 = *(const short8*)((char*)hL + swz(r0, 2 * kc + q5));
          short8 bh1 = *(const short8*)((char*)hL + swz(r1, 2 * kc + q5));
          ka0 = MF(avM, bh0, ka0);
          va0 = MF(bh0, avV, va0);
          ka1 = MF(avM, bh1, ka1);
          va1 = MF(bh1, avV, va1);
        }
        // kh stores: regs 4qd..4qd+3 -> frow = 32mtv + 8qd + 4q5 + (0..3): one 8B chunk
#pragma unroll
        for (int j = 0; j < 2; ++j){
          floatx16 ka = j ? ka1 : ka0;
          int tloc = 32 * (ntv0 + j) + l31;
#pragma unroll
          for (int qd = 0; qd < 4; ++qd){
            u32x2 pv;
            pv.x = pk2(ka[4 * qd + 0], ka[4 * qd + 1]);
            pv.y = pk2(ka[4 * qd + 2], ka[4 * qd + 3]);
            *(u32x2*)((char*)khL + swz(tloc, 4 * mtv + qd) + 8 * q5) = pv;
          }
        }
        // v stores (operand-swapped D[t][d]): lane -> d row, regs -> consecutive t
#pragma unroll
        for (int j = 0; j < 2; ++j){
          floatx16 va = j ? va1 : va0;
#pragma unroll
          for (int qd = 0; qd < 4; ++qd){
            u32x2 pv;
            pv.x = pk2(va[4 * qd + 0] + vbl, va[4 * qd + 1] + vbl);
            pv.y = pk2(va[4 * qd + 2] + vbl, va[4 * qd + 3] + vbl);
            *(u32x2*)((char*)vt + swz(32 * mtv + l31, 4 * (ntv0 + j) + qd) + 8 * q5) = pv;
          }
        }
      }
      __syncthreads();               // khL, vt complete
      // ---- scores + exp + P@V, one 32-t subtile live at a time
      // q-fragments are mt-invariant: hoist (reused 4x)
      short8 bqr[8];
#pragma unroll
      for (int kc = 0; kc < 8; ++kc)
        bqr[kc] = *(const short8*)((char*)hL + swz(32 * w + l31, 2 * kc + q5));
#pragma unroll 1
      for (int mt = 0; mt < 4; ++mt){
        floatx16 sae = fz(), sao = fz();   // even/odd kc chains (halved dep path)
        __builtin_amdgcn_s_setprio(1);
#pragma unroll
        for (int kc2 = 0; kc2 < 4; ++kc2){
          short8 ak0 = *(const short8*)((char*)khL + swz(32 * mt + l31, 4 * kc2 + q5));
          short8 ak1 = *(const short8*)((char*)khL + swz(32 * mt + l31, 4 * kc2 + 2 + q5));
          sae = MF(ak0, bqr[2 * kc2 + 0], sae);
          sao = MF(ak1, bqr[2 * kc2 + 1], sao);
        }
        __builtin_amdgcn_s_setprio(0);
        floatx16 sa = sae + sao;
#pragma unroll
        for (int reg = 0; reg < 16; ++reg){
          int trl = 32 * mt + (reg & 3) + 8 * (reg >> 2) + 4 * q5;
          int tg = t0 + trl;
          float lk = (tg == scol) ? 0.f : LKOFF;
          float v = sa[reg] + c_all[tg] + lk;
          v = fminf(fmaxf(v, -50.f), 50.f);
          float p = __expf(v - 8.f);   // fixed max: softmax shift-invariant
          sa[reg] = p;
          ls_tot += p;
        }
        // pf frags computed BEFORE the bv loads so sa dies here (register diet)
        short8 pf0 = frag_from(sa, 0, q5);
        short8 pf1 = frag_from(sa, 1, q5);
        __builtin_amdgcn_s_setprio(1);
#pragma unroll
        for (int nt = 0; nt < 4; ++nt){
          short8 bv0 = *(const short8*)((char*)vt + swz(32 * nt + l31, 2 * (2 * mt + 0) + q5));
          oacc[nt] = MF(pf0, bv0, oacc[nt]);
          short8 bv1 = *(const short8*)((char*)vt + swz(32 * nt + l31, 2 * (2 * mt + 1) + q5));
          oacc[nt] = MF(pf1, bv1, oacc[nt]);
        }
        __builtin_amdgcn_s_setprio(0);
      }
    }
    __syncthreads();                   // all hL reads done before epilogue writes

    // ---- epilogue: /l, +residual, LayerNorm, write back to hL (own rows only)
    float l_run = ls_tot + __shfl_xor(ls_tot, 32);
    float linv = 1.f / l_run;
    float gv[4], bbv[4];
#pragma unroll
    for (int nt = 0; nt < 4; ++nt){
      gv[nt]  = ldf(lng, (size_t)li * 128 + 32 * nt + l31, fl);
      bbv[nt] = ldf(lnb, (size_t)li * 128 + 32 * nt + l31, fl);
    }
#pragma unroll
    for (int reg = 0; reg < 16; ++reg){
      int rr = (reg & 3) + 8 * (reg >> 2) + 4 * q5;
      int srow = 32 * w + rr;
      float lrv = __shfl(linv, rr);
      float s1 = 0.f, s2 = 0.f;
#pragma unroll
      for (int nt = 0; nt < 4; ++nt){
        int d = 32 * nt + l31;
        float res = b2f(*(const u16*)((char*)hL + swz(srow, d >> 3) + (d & 7) * 2));
        float v = oacc[nt][reg] * lrv + res;
        oacc[nt][reg] = v;
        s1 += v; s2 += v * v;
      }
#pragma unroll
      for (int off = 1; off < 32; off <<= 1){ s1 += __shfl_xor(s1, off); s2 += __shfl_xor(s2, off); }
      float mu = s1 * 0.0078125f;
      float rs = rsqrtf(fmaxf(s2 * 0.0078125f - mu * mu, 0.f) + 1e-5f);
#pragma unroll
      for (int nt = 0; nt < 4; ++nt){
        int d = 32 * nt + l31;
        float v = (oacc[nt][reg] - mu) * rs * gv[nt] + bbv[nt];
        *(u16*)((char*)hL + swz(srow, d >> 3) + (d & 7) * 2) = f2b(v);
      }
    }
    __syncthreads();                   // hL update visible before next layer / store
  }

  // final h -> global, coalesced 16B chunks
#pragma unroll
  for (int it = 0; it < 8; ++it){
    int c = it * 512 + tid, row = c >> 4, ch = c & 15;
    *(short8*)(hgq + (size_t)bl * 32768 + row * 128 + ch * 8) =
        *(const short8*)((char*)hL + swz(row, ch));
  }
}

// ---------------- MLP head ----------------

__global__ __launch_bounds__(256) void k_mlp1(const u16* se, const u16* hgq, const u16* h1WT,
                                              float* part, int qoff, int nb){
  int mb = blockIdx.x, ks = blockIdx.y;
  int tid = threadIdx.x, w = tid >> 6, lane = tid & 63, l31 = lane & 31, q5 = lane >> 5;
  int b0 = mb * 32;
  floatx16 acc = fz();
  const u16* brow = h1WT + (size_t)(32 * w + l31) * 32896;
  int br = b0 + l31;
  const u16* seb = se + (size_t)(qoff + br) * 128;
  const u16* hb = hgq + (size_t)br * 32768;
  for (int kk = 0; kk < 257; ++kk){
    int kbase = ks * 4112 + kk * 16;
    const u16* ap = (kbase < 128) ? (seb + kbase + q5 * 8) : (hb + (kbase - 128) + q5 * 8);
    short8 a = *(const short8*)ap;
    short8 bf = *(const short8*)(brow + kbase + q5 * 8);
    acc = MF(a, bf, acc);
  }
#pragma unroll
  for (int reg = 0; reg < 16; ++reg){
    int rr = (reg & 3) + 8 * (reg >> 2) + 4 * q5;
    part[(size_t)ks * nb * 128 + (size_t)(b0 + rr) * 128 + 32 * w + l31] = acc[reg];
  }
}

__global__ __launch_bounds__(256) void k_mlp1red(const float* part, const u16* h1b, float* z1q,
                                                 const int* dflag, int nb){
  int fl = dflag[0];
  int idx = blockIdx.x * 256 + threadIdx.x;    // 0..nb*128-1
  float s = ldf(h1b, idx & 127, fl);
  size_t stride = (size_t)nb * 128;
#pragma unroll
  for (int ks = 0; ks < 8; ++ks) s += part[(size_t)ks * stride + idx];
  z1q[idx] = fmaxf(s, 0.f);
}

__global__ __launch_bounds__(256) void k_mlp2(const float* z1, const u16* h2W, const u16* h2b,
                                              float* z2, const int* dflag){
  int fl = dflag[0];
  int idx = blockIdx.x * 256 + threadIdx.x;    // 0..131071
  int b = idx >> 6, j = idx & 63;
  float s = ldf(h2b, j, fl);
  const float* zr = z1 + (size_t)b * 128;
  for (int k = 0; k < 128; ++k) s += zr[k] * ldf(h2W, (size_t)k * 64 + j, fl);
  z2[idx] = fmaxf(s, 0.f);
}

__global__ __launch_bounds__(256) void k_mlp3(const float* z2, const u16* h3W, const u16* h3b,
                                              void* out, const int* dflag){
  int fl = dflag[0];
  int b = blockIdx.x * 256 + threadIdx.x;      // 0..2047
  float s = ldf(h3b, 0, fl);
  const float* zr = z2 + (size_t)b * 64;
#pragma unroll
  for (int j = 0; j < 64; ++j) s += zr[j] * ldf(h3W, j, fl);
  if (!__builtin_isfinite(s)) s = 0.f;
  if (fl) ((float*)out)[b] = s;
  else    ((u16*)out)[b] = f2b(s);
}

// ---------------- launch ----------------

extern "C" void kernel_launch(void* const* d_in, const int* in_sizes, int n_in,
                              void* d_out, int out_size, void* d_ws, size_t ws_size,
                              hipStream_t stream) {
  const u16* x   = (const u16*)d_in[0];
  const u16* sW  = (const u16*)d_in[1];
  const u16* sb  = (const u16*)d_in[2];
  const u16* hW  = (const u16*)d_in[3];
  const u16* hb  = (const u16*)d_in[4];
  const u16* qW  = (const u16*)d_in[5];
  const u16* qb  = (const u16*)d_in[6];
  const u16* kW  = (const u16*)d_in[7];
  // d_in[8] = kb : cancels in softmax, unused
  const u16* vW  = (const u16*)d_in[9];
  const u16* vb  = (const u16*)d_in[10];
  const u16* lng = (const u16*)d_in[11];
  const u16* lnb = (const u16*)d_in[12];
  const u16* h1W = (const u16*)d_in[13];
  const u16* h1b = (const u16*)d_in[14];
  const u16* h2W = (const u16*)d_in[15];
  const u16* h2b = (const u16*)d_in[16];
  const u16* h3W = (const u16*)d_in[17];
  const u16* h3b = (const u16*)d_in[18];

  // full-pass mode (r5-r8 ran this branch); quarter mode fallback.
  const int nb = (ws_size >= 153600000ull) ? 2048 : 512;
  const int nq = 2048 / nb;

  char* W = (char*)d_ws;
  size_t o = 0;
  u16*   hg    = (u16*)(W + o); o += (size_t)nb * 65536;   // nb*32768*2
  u16*   h1WT  = (u16*)(W + o); o += 8421376;
  u16*   se    = (u16*)(W + o); o += 524288;               // always full 2048x128 bf16
  u16*   Mrow  = (u16*)(W + o); o += 65536;
  u16*   vWT   = (u16*)(W + o); o += 65536;
  float* uv    = (float*)(W + o); o += 1024;
  float* part  = (float*)(W + o); o += (size_t)nb * 4096;  // 8 * nb*128 * 4B
  float* z1    = (float*)(W + o); o += 1048576;            // always full
  float* z2    = (float*)(W + o); o += 524288;
  int*   dflag = (int*)(W + o);

  k_detect<<<1, 256, 0, stream>>>(x, dflag);
  k_prepw<<<256, 128, 0, stream>>>(qW, kW, vW, qb, Mrow, vWT, uv, dflag);
  k_h1t<<<514, 256, 0, stream>>>(h1W, h1WT, dflag);

  for (int q = 0; q < nq; ++q){
    int qoff = q * nb;
    k_fan<<<nb, 512, 0, stream>>>(x, sW, sb, hW, hb, Mrow, uv, vWT, vb,
                                  lng, lnb, hg, se, qoff, dflag);
    k_mlp1<<<dim3(nb / 32, 8), 256, 0, stream>>>(se, hg, h1WT, part, qoff, nb);
    k_mlp1red<<<nb / 2, 256, 0, stream>>>(part, h1b, z1 + (size_t)qoff * 128, dflag, nb);
  }

  k_mlp2<<<512, 256, 0, stream>>>(z1, h2W, h2b, z2, dflag);
  k_mlp3<<<8, 256, 0, stream>>>(z2, h3W, h3b, d_out, dflag);
}

// Round 5
// 1045.801 us; speedup vs baseline: 1.5627x; 1.0256x over previous
//
#include <hip/hip_runtime.h>
#include <cstddef>

// FAN_39273180955145 — round 15. r14 post-mortem: merged kh+v phase won
// (854us vs r10's 921) but held ka0/ka1/va0/va1 (64 accums) + oacc (64) =
// 128 accum + 128 arch = exactly the 256-reg cap -> ~330MB/dispatch scratch
// (FETCH 103MB, WRITE 385MB). Fix: un-merge into Phase A (kh, ka0/ka1 dual
// chains) + Phase B (v, va0/va1 dual chains) -> 96-accum peak everywhere,
// spill-free, at the cost of one extra hL read pass (16 ds_read_b128/wave/
// tile). Kept from r14: operand-swapped packed-b64 vt stores, bqr q-frag
// hoist, even/odd score chains, setprio around MFMA clusters,
// __launch_bounds__(512,2).
// Math identical to r8/r10 (passed, absmax 9.8e-4): S[s,t]=sum_f h[s,f]kh[t,f]
// +c_t, kh[t,f]=sum_e M'[f,e]h[t,e]; analytic 2-value log-kernel; fixed-max
// softmax p=exp(s-8); dtype detector; h in LDS; 1 block = 1 batch.

typedef unsigned short u16;
typedef unsigned int u32;
typedef short short8 __attribute__((ext_vector_type(8)));
typedef u32 u32x2 __attribute__((ext_vector_type(2)));
typedef float floatx16 __attribute__((ext_vector_type(16)));

__device__ __forceinline__ float b2f(u16 u){ return __uint_as_float(((u32)u) << 16); }
__device__ __forceinline__ u16 f2b(float f){
  u32 u = __float_as_uint(f);
  return (u16)((u + 0x7fffu + ((u >> 16) & 1u)) >> 16);
}
// flagged input load: f32 ? fp32 : bf16; non-finite -> 0
__device__ __forceinline__ float ldf(const u16* p, size_t i, int f32){
  float v = f32 ? ((const float*)p)[i] : b2f(p[i]);
  return __builtin_isfinite(v) ? v : 0.f;
}
__device__ __forceinline__ u32 pk2(float a, float b){
  return ((u32)f2b(b) << 16) | (u32)f2b(a);
}
// [rows][128 bf16] LDS region, 256B rows, 16B-chunk xor swizzle (2-way max = free)
__device__ __forceinline__ int swz(int row, int ch){ return (row << 8) | ((ch ^ (row & 15)) << 4); }
__device__ __forceinline__ floatx16 fz(){
  floatx16 z;
#pragma unroll
  for (int i = 0; i < 16; ++i) z[i] = 0.f;
  return z;
}
__device__ __forceinline__ floatx16 MF(short8 a, short8 b, floatx16 c){
  return __builtin_amdgcn_mfma_f32_32x32x16_bf16(a, b, c, 0, 0, 0);
}
// C-layout 32x32 tile (by value) -> k-chunk A-fragment via xor-32 exchange (r4-verified).
__device__ __forceinline__ short8 frag_from(floatx16 cv, int half, int q5){
  int r0 = half * 8;
  u32 e01 = pk2(cv[r0 + 0], cv[r0 + 1]);
  u32 e23 = pk2(cv[r0 + 2], cv[r0 + 3]);
  u32 o01 = pk2(cv[r0 + 4], cv[r0 + 5]);
  u32 o23 = pk2(cv[r0 + 6], cv[r0 + 7]);
  u32 s0 = q5 ? e01 : o01;
  u32 s1 = q5 ? e23 : o23;
  u32 r0v = __shfl_xor(s0, 32);
  u32 r1v = __shfl_xor(s1, 32);
  union { u32 u[4]; short8 v; } un;
  un.u[0] = q5 ? r0v : e01;
  un.u[1] = q5 ? r1v : e23;
  un.u[2] = q5 ? o01 : r0v;
  un.u[3] = q5 ? o23 : r1v;
  return un.v;
}

// ---------------- dtype detector (r4-verified) ----------------
__global__ __launch_bounds__(256) void k_detect(const u16* x, int* dflag){
  __shared__ int red[256];
  int t = threadIdx.x, cnt = 0;
  for (int i = t; i < 4096; i += 256){
    u16 v = x[2 * i];
    int e = (v >> 7) & 0xFF;
    if (e == 0xFF || e >= 0x90 || (e > 0 && e <= 0x20)) ++cnt;
  }
  red[t] = cnt;
  __syncthreads();
  for (int off = 128; off > 0; off >>= 1){
    if (t < off) red[t] += red[t + off];
    __syncthreads();
  }
  if (t == 0) dflag[0] = (red[0] > 1000) ? 1 : 0;
}

// ---------------- prep kernels ----------------

// Mrow[r][c] = M'[r,c] (row-major, kh A-operand); vWT[d][e] = vW[e][d]; uv = u'.
__global__ __launch_bounds__(128) void k_prepw(const u16* qW, const u16* kW, const u16* vW,
                                               const u16* qb, u16* Mrow, u16* vWT, float* uv,
                                               const int* dflag){
  int fl = dflag[0];
  int i = blockIdx.x >> 7, f = blockIdx.x & 127, e = threadIdx.x;
  size_t qo = (size_t)(i * 128 + e) * 128;   // qW row e
  size_t ko = (size_t)(i * 128 + f) * 128;   // kW row f
  float m = 0.f;
  for (int d = 0; d < 128; ++d) m += ldf(qW, qo + d, fl) * ldf(kW, ko + d, fl);
  const float RS = 0.08838834764831845f;  // 1/sqrt(128)
  Mrow[(i * 128 + e) * 128 + f] = f2b(m * RS);                // M'[e,f] at [e][f]
  vWT[(i * 128 + f) * 128 + e] = f2b(ldf(vW, qo + f, fl));    // vWT[d][e] = vW[e][d]
  __shared__ float red[128];
  red[e] = ldf(kW, ko + e, fl) * ldf(qb, (size_t)i * 128 + e, fl);
  __syncthreads();
  for (int off = 64; off > 0; off >>= 1){
    if (e < off) red[e] += red[e + off];
    __syncthreads();
  }
  if (e == 0) uv[i * 128 + f] = red[0] * RS;
}

__global__ __launch_bounds__(256) void k_h1t(const u16* h1W, u16* h1WT, const int* dflag){
  int fl = dflag[0];
  __shared__ u16 tile[64][130];
  int k0 = blockIdx.x * 64, tid = threadIdx.x;
#pragma unroll 4
  for (int it = 0; it < 32; ++it){
    int r = it * 2 + (tid >> 7), c = tid & 127;
    tile[r][c] = f2b(ldf(h1W, (size_t)(k0 + r) * 128 + c, fl));
  }
  __syncthreads();
#pragma unroll 4
  for (int it = 0; it < 32; ++it){
    int idx = it * 256 + tid, n = idx >> 6, kk = idx & 63;
    h1WT[(size_t)n * 32896 + k0 + kk] = tile[kk][n];
  }
}

// -------- fused embed + 2 attention layers; h in LDS; one block = one batch --------

__global__ __launch_bounds__(512, 2) void k_fan(
    const u16* x, const u16* sW, const u16* sb, const u16* hW, const u16* hbe,
    const u16* Mrow, const float* uv, const u16* vWT, const u16* vb,
    const u16* lng, const u16* lnb,
    u16* hgq, u16* se, int qoff, const int* dflag){
  __shared__ alignas(16) u16 hL[32768];    // h   [256 s][128 f], swz, 64KB
  __shared__ alignas(16) u16 vt[16384];    // vT  [128 d][128 t], swz, 32KB
  __shared__ alignas(16) u16 khL[16384];   // kh  [128 t][128 f], swz, 32KB
  __shared__ float c_all[256];             // c_t, whole layer
  __shared__ float u_lds[128];             // u' for current layer
  int fl = dflag[0];
  int bl = blockIdx.x;
  int b = qoff + bl;
  int tid = threadIdx.x, w = tid >> 6, lane = tid & 63, l31 = lane & 31, q5 = lane >> 5;
  size_t xo = (size_t)b * 272;
  const float LKOFF = -20.72326584f;       // ln(1e-9); off-diag log-kernel value

  // scalar embedding (lanes 0..127)
  if (tid < 128){
    float acc = ldf(sb, tid, fl);
#pragma unroll
    for (int j = 0; j < 16; ++j) acc += ldf(x, xo + j, fl) * ldf(sW, (size_t)j * 128 + tid, fl);
    se[(size_t)b * 128 + tid] = f2b(acc);
  }
  // history embedding -> hL
#pragma unroll
  for (int it = 0; it < 8; ++it){
    int c = it * 512 + tid, s = c >> 4, ch = c & 15;
    float xv = ldf(x, xo + 16 + s, fl);
    short8 r;
#pragma unroll
    for (int j = 0; j < 8; ++j)
      r[j] = (short)f2b(xv * ldf(hW, ch * 8 + j, fl) + ldf(hbe, ch * 8 + j, fl));
    *(short8*)((char*)hL + swz(s, ch)) = r;
  }

#pragma unroll 1
  for (int li = 0; li < 2; ++li){
    const u16* Mri  = Mrow + li * 16384;
    const u16* vWTi = vWT + li * 16384;
    if (tid < 128) u_lds[tid] = uv[li * 128 + tid];
    __syncthreads();                 // hL (embed/prev epilogue) + u_lds visible

    // ---- c_all[t] = u'.h_t for all 256 rows; MFMA-operand access pattern (2-way, free)
    {
      int row = 32 * w + l31;
      float dot = 0.f;
#pragma unroll 2
      for (int kc = 0; kc < 8; ++kc){
        int ch = 2 * kc + q5;
        short8 hv = *(const short8*)((char*)hL + swz(row, ch));
#pragma unroll
        for (int j = 0; j < 8; ++j) dot += u_lds[ch * 8 + j] * b2f(hv[j]);
      }
      dot += __shfl_xor(dot, 32);
      if (q5 == 0) c_all[row] = dot;
    }

    float ls_tot = 0.f;
    floatx16 oacc[4];
#pragma unroll
    for (int nt = 0; nt < 4; ++nt) oacc[nt] = fz();
    int scol = 32 * w + l31;

#pragma unroll 1
    for (int tt = 0; tt < 2; ++tt){
      int t0 = tt * 128;
      __syncthreads();               // prior tile's khL/vt reads done; c_all visible
      int mtv = w & 3, ntv0 = (w >> 2) * 2;
      int r0 = t0 + 32 * ntv0 + l31, r1 = r0 + 32;
      // ---- Phase A: kh-tile, dual-row chains (ka0/ka1); accum peak oacc+32
      // kh[t][f] = sum_e M'[f,e] h[t,e]  (A=Mrow rows, B=h rows)
      {
        const u16* Ma = Mri + (32 * mtv + l31) * 128 + q5 * 8;
        floatx16 ka0 = fz(), ka1 = fz();
#pragma unroll 2
        for (int kc = 0; kc < 8; ++kc){
          short8 avM = *(const short8*)(Ma + kc * 16);
          short8 bh0 = *(const short8*)((char*)hL + swz(r0, 2 * kc + q5));
          short8 bh1 = *(const short8*)((char*)hL + swz(r1, 2 * kc + q5));
          ka0 = MF(avM, bh0, ka0);
          ka1 = MF(avM, bh1, ka1);
        }
        // kh stores: regs 4qd..4qd+3 -> frow = 32mtv + 8qd + 4q5 + (0..3): one 8B chunk
#pragma unroll
        for (int j = 0; j < 2; ++j){
          floatx16 ka = j ? ka1 : ka0;
          int tloc = 32 * (ntv0 + j) + l31;
#pragma unroll
          for (int qd = 0; qd < 4; ++qd){
            u32x2 pv;
            pv.x = pk2(ka[4 * qd + 0], ka[4 * qd + 1]);
            pv.y = pk2(ka[4 * qd + 2], ka[4 * qd + 3]);
            *(u32x2*)((char*)khL + swz(tloc, 4 * mtv + qd) + 8 * q5) = pv;
          }
        }
      }
      // ---- Phase B: v-tile, operand-swapped (D[t][d]), dual-row chains
      // v[t][d] = sum_e h[t,e] vW[e,d]  (A=h rows, B=vWT rows)
      {
        const u16* Va = vWTi + (32 * mtv + l31) * 128 + q5 * 8;
        float vbl = ldf(vb, (size_t)li * 128 + 32 * mtv + l31, fl);
        floatx16 va0 = fz(), va1 = fz();
#pragma unroll 2
        for (int kc = 0; kc < 8; ++kc){
          short8 avV = *(const short8*)(Va + kc * 16);
          short8 bh0 = *(const short8*)((char*)hL + swz(r0, 2 * kc + q5));
          short8 bh1 = *(const short8*)((char*)hL + swz(r1, 2 * kc + q5));
          va0 = MF(bh0, avV, va0);
          va1 = MF(bh1, avV, va1);
        }
        // v stores: lane -> d row, regs -> consecutive t; lane-local bias
#pragma unroll
        for (int j = 0; j < 2; ++j){
          floatx16 va = j ? va1 : va0;
#pragma unroll
          for (int qd = 0; qd < 4; ++qd){
            u32x2 pv;
            pv.x = pk2(va[4 * qd + 0] + vbl, va[4 * qd + 1] + vbl);
            pv.y = pk2(va[4 * qd + 2] + vbl, va[4 * qd + 3] + vbl);
            *(u32x2*)((char*)vt + swz(32 * mtv + l31, 4 * (ntv0 + j) + qd) + 8 * q5) = pv;
          }
        }
      }
      __syncthreads();               // khL, vt complete
      // ---- scores + exp + P@V, one 32-t subtile live at a time
      // q-fragments are mt-invariant: hoist (reused 4x)
      short8 bqr[8];
#pragma unroll
      for (int kc = 0; kc < 8; ++kc)
        bqr[kc] = *(const short8*)((char*)hL + swz(32 * w + l31, 2 * kc + q5));
#pragma unroll 1
      for (int mt = 0; mt < 4; ++mt){
        floatx16 sae = fz(), sao = fz();   // even/odd kc chains (halved dep path)
        __builtin_amdgcn_s_setprio(1);
#pragma unroll
        for (int kc2 = 0; kc2 < 4; ++kc2){
          short8 ak0 = *(const short8*)((char*)khL + swz(32 * mt + l31, 4 * kc2 + q5));
          short8 ak1 = *(const short8*)((char*)khL + swz(32 * mt + l31, 4 * kc2 + 2 + q5));
          sae = MF(ak0, bqr[2 * kc2 + 0], sae);
          sao = MF(ak1, bqr[2 * kc2 + 1], sao);
        }
        __builtin_amdgcn_s_setprio(0);
        floatx16 sa = sae + sao;
#pragma unroll
        for (int reg = 0; reg < 16; ++reg){
          int trl = 32 * mt + (reg & 3) + 8 * (reg >> 2) + 4 * q5;
          int tg = t0 + trl;
          float lk = (tg == scol) ? 0.f : LKOFF;
          float v = sa[reg] + c_all[tg] + lk;
          v = fminf(fmaxf(v, -50.f), 50.f);
          float p = __expf(v - 8.f);   // fixed max: softmax shift-invariant
          sa[reg] = p;
          ls_tot += p;
        }
        // pf frags computed BEFORE the bv loads so sa dies here (register diet)
        short8 pf0 = frag_from(sa, 0, q5);
        short8 pf1 = frag_from(sa, 1, q5);
        __builtin_amdgcn_s_setprio(1);
#pragma unroll
        for (int nt = 0; nt < 4; ++nt){
          short8 bv0 = *(const short8*)((char*)vt + swz(32 * nt + l31, 2 * (2 * mt + 0) + q5));
          oacc[nt] = MF(pf0, bv0, oacc[nt]);
          short8 bv1 = *(const short8*)((char*)vt + swz(32 * nt + l31, 2 * (2 * mt + 1) + q5));
          oacc[nt] = MF(pf1, bv1, oacc[nt]);
        }
        __builtin_amdgcn_s_setprio(0);
      }
    }
    __syncthreads();                   // all hL reads done before epilogue writes

    // ---- epilogue: /l, +residual, LayerNorm, write back to hL (own rows only)
    float l_run = ls_tot + __shfl_xor(ls_tot, 32);
    float linv = 1.f / l_run;
    float gv[4], bbv[4];
#pragma unroll
    for (int nt = 0; nt < 4; ++nt){
      gv[nt]  = ldf(lng, (size_t)li * 128 + 32 * nt + l31, fl);
      bbv[nt] = ldf(lnb, (size_t)li * 128 + 32 * nt + l31, fl);
    }
#pragma unroll
    for (int reg = 0; reg < 16; ++reg){
      int rr = (reg & 3) + 8 * (reg >> 2) + 4 * q5;
      int srow = 32 * w + rr;
      float lrv = __shfl(linv, rr);
      float s1 = 0.f, s2 = 0.f;
#pragma unroll
      for (int nt = 0; nt < 4; ++nt){
        int d = 32 * nt + l31;
        float res = b2f(*(const u16*)((char*)hL + swz(srow, d >> 3) + (d & 7) * 2));
        float v = oacc[nt][reg] * lrv + res;
        oacc[nt][reg] = v;
        s1 += v; s2 += v * v;
      }
#pragma unroll
      for (int off = 1; off < 32; off <<= 1){ s1 += __shfl_xor(s1, off); s2 += __shfl_xor(s2, off); }
      float mu = s1 * 0.0078125f;
      float rs = rsqrtf(fmaxf(s2 * 0.0078125f - mu * mu, 0.f) + 1e-5f);
#pragma unroll
      for (int nt = 0; nt < 4; ++nt){
        int d = 32 * nt + l31;
        float v = (oacc[nt][reg] - mu) * rs * gv[nt] + bbv[nt];
        *(u16*)((char*)hL + swz(srow, d >> 3) + (d & 7) * 2) = f2b(v);
      }
    }
    __syncthreads();                   // hL update visible before next layer / store
  }

  // final h -> global, coalesced 16B chunks
#pragma unroll
  for (int it = 0; it < 8; ++it){
    int c = it * 512 + tid, row = c >> 4, ch = c & 15;
    *(short8*)(hgq + (size_t)bl * 32768 + row * 128 + ch * 8) =
        *(const short8*)((char*)hL + swz(row, ch));
  }
}

// ---------------- MLP head ----------------

__global__ __launch_bounds__(256) void k_mlp1(const u16* se, const u16* hgq, const u16* h1WT,
                                              float* part, int qoff, int nb){
  int mb = blockIdx.x, ks = blockIdx.y;
  int tid = threadIdx.x, w = tid >> 6, lane = tid & 63, l31 = lane & 31, q5 = lane >> 5;
  int b0 = mb * 32;
  floatx16 acc = fz();
  const u16* brow = h1WT + (size_t)(32 * w + l31) * 32896;
  int br = b0 + l31;
  const u16* seb = se + (size_t)(qoff + br) * 128;
  const u16* hb = hgq + (size_t)br * 32768;
  for (int kk = 0; kk < 257; ++kk){
    int kbase = ks * 4112 + kk * 16;
    const u16* ap = (kbase < 128) ? (seb + kbase + q5 * 8) : (hb + (kbase - 128) + q5 * 8);
    short8 a = *(const short8*)ap;
    short8 bf = *(const short8*)(brow + kbase + q5 * 8);
    acc = MF(a, bf, acc);
  }
#pragma unroll
  for (int reg = 0; reg < 16; ++reg){
    int rr = (reg & 3) + 8 * (reg >> 2) + 4 * q5;
    part[(size_t)ks * nb * 128 + (size_t)(b0 + rr) * 128 + 32 * w + l31] = acc[reg];
  }
}

__global__ __launch_bounds__(256) void k_mlp1red(const float* part, const u16* h1b, float* z1q,
                                                 const int* dflag, int nb){
  int fl = dflag[0];
  int idx = blockIdx.x * 256 + threadIdx.x;    // 0..nb*128-1
  float s = ldf(h1b, idx & 127, fl);
  size_t stride = (size_t)nb * 128;
#pragma unroll
  for (int ks = 0; ks < 8; ++ks) s += part[(size_t)ks * stride + idx];
  z1q[idx] = fmaxf(s, 0.f);
}

__global__ __launch_bounds__(256) void k_mlp2(const float* z1, const u16* h2W, const u16* h2b,
                                              float* z2, const int* dflag){
  int fl = dflag[0];
  int idx = blockIdx.x * 256 + threadIdx.x;    // 0..131071
  int b = idx >> 6, j = idx & 63;
  float s = ldf(h2b, j, fl);
  const float* zr = z1 + (size_t)b * 128;
  for (int k = 0; k < 128; ++k) s += zr[k] * ldf(h2W, (size_t)k * 64 + j, fl);
  z2[idx] = fmaxf(s, 0.f);
}

__global__ __launch_bounds__(256) void k_mlp3(const float* z2, const u16* h3W, const u16* h3b,
                                              void* out, const int* dflag){
  int fl = dflag[0];
  int b = blockIdx.x * 256 + threadIdx.x;      // 0..2047
  float s = ldf(h3b, 0, fl);
  const float* zr = z2 + (size_t)b * 64;
#pragma unroll
  for (int j = 0; j < 64; ++j) s += zr[j] * ldf(h3W, j, fl);
  if (!__builtin_isfinite(s)) s = 0.f;
  if (fl) ((float*)out)[b] = s;
  else    ((u16*)out)[b] = f2b(s);
}

// ---------------- launch ----------------

extern "C" void kernel_launch(void* const* d_in, const int* in_sizes, int n_in,
                              void* d_out, int out_size, void* d_ws, size_t ws_size,
                              hipStream_t stream) {
  const u16* x   = (const u16*)d_in[0];
  const u16* sW  = (const u16*)d_in[1];
  const u16* sb  = (const u16*)d_in[2];
  const u16* hW  = (const u16*)d_in[3];
  const u16* hb  = (const u16*)d_in[4];
  const u16* qW  = (const u16*)d_in[5];
  const u16* qb  = (const u16*)d_in[6];
  const u16* kW  = (const u16*)d_in[7];
  // d_in[8] = kb : cancels in softmax, unused
  const u16* vW  = (const u16*)d_in[9];
  const u16* vb  = (const u16*)d_in[10];
  const u16* lng = (const u16*)d_in[11];
  const u16* lnb = (const u16*)d_in[12];
  const u16* h1W = (const u16*)d_in[13];
  const u16* h1b = (const u16*)d_in[14];
  const u16* h2W = (const u16*)d_in[15];
  const u16* h2b = (const u16*)d_in[16];
  const u16* h3W = (const u16*)d_in[17];
  const u16* h3b = (const u16*)d_in[18];

  // full-pass mode (r5-r8 ran this branch); quarter mode fallback.
  const int nb = (ws_size >= 153600000ull) ? 2048 : 512;
  const int nq = 2048 / nb;

  char* W = (char*)d_ws;
  size_t o = 0;
  u16*   hg    = (u16*)(W + o); o += (size_t)nb * 65536;   // nb*32768*2
  u16*   h1WT  = (u16*)(W + o); o += 8421376;
  u16*   se    = (u16*)(W + o); o += 524288;               // always full 2048x128 bf16
  u16*   Mrow  = (u16*)(W + o); o += 65536;
  u16*   vWT   = (u16*)(W + o); o += 65536;
  float* uv    = (float*)(W + o); o += 1024;
  float* part  = (float*)(W + o); o += (size_t)nb * 4096;  // 8 * nb*128 * 4B
  float* z1    = (float*)(W + o); o += 1048576;            // always full
  float* z2    = (float*)(W + o); o += 524288;
  int*   dflag = (int*)(W + o);

  k_detect<<<1, 256, 0, stream>>>(x, dflag);
  k_prepw<<<256, 128, 0, stream>>>(qW, kW, vW, qb, Mrow, vWT, uv, dflag);
  k_h1t<<<514, 256, 0, stream>>>(h1W, h1WT, dflag);

  for (int q = 0; q < nq; ++q){
    int qoff = q * nb;
    k_fan<<<nb, 512, 0, stream>>>(x, sW, sb, hW, hb, Mrow, uv, vWT, vb,
                                  lng, lnb, hg, se, qoff, dflag);
    k_mlp1<<<dim3(nb / 32, 8), 256, 0, stream>>>(se, hg, h1WT, part, qoff, nb);
    k_mlp1red<<<nb / 2, 256, 0, stream>>>(part, h1b, z1 + (size_t)qoff * 128, dflag, nb);
  }

  k_mlp2<<<512, 256, 0, stream>>>(z1, h2W, h2b, z2, dflag);
  k_mlp3<<<8, 256, 0, stream>>>(z2, h3W, h3b, d_out, dflag);
}